// Round 7
// baseline (2484.837 us; speedup 1.0000x reference)
//
#include <hip/hip_runtime.h>
#include <cmath>

#define B_   4
#define N_   2466
#define R_   (B_*N_)     // 9864
#define ELLW 96

typedef __attribute__((ext_vector_type(8))) short bf16x8;
typedef __attribute__((ext_vector_type(4))) float f32x4;

__device__ __forceinline__ unsigned short bf16_rne(float x) {
  union { float f; unsigned u; } c; c.f = x;
  unsigned r = c.u + 0x7FFFu + ((c.u >> 16) & 1u);
  return (unsigned short)(r >> 16);
}
__device__ __forceinline__ float bf16_back(unsigned short h) {
  union { float f; unsigned u; } c; c.u = ((unsigned)h) << 16;
  return c.f;
}

// ============ fused pre-kernel: transposes + ELL + W hi/lo fragment split ============
__global__ __launch_bounds__(256) void k_pre(
    const float* __restrict__ c2, const float* __restrict__ c3,
    const float* __restrict__ c4, const float* __restrict__ c5,
    float* __restrict__ t0, float* __restrict__ t1,
    float* __restrict__ t2, float* __restrict__ t3,
    const float* __restrict__ adj, int* __restrict__ cols, int* __restrict__ cnts,
    const float* __restrict__ lin_w,
    unsigned short* __restrict__ whi, unsigned short* __restrict__ wlo) {
  __shared__ float t[32][33];
  int bid = blockIdx.x;
  if (bid < 6144) {
    const float* in; float* out; int C, P, nx, ny, rem;
    if (bid < 3136)      { in = c2; out = t0; C = 256;  P = 3136; nx = 98; ny = 8;  rem = bid; }
    else if (bid < 4736) { in = c3; out = t1; C = 512;  P = 784;  nx = 25; ny = 16; rem = bid - 3136; }
    else if (bid < 5632) { in = c4; out = t2; C = 1024; P = 196;  nx = 7;  ny = 32; rem = bid - 4736; }
    else                 { in = c5; out = t3; C = 2048; P = 49;   nx = 2;  ny = 64; rem = bid - 5632; }
    int x = rem % nx; int tq = rem / nx; int y = tq % ny; int b = tq / ny;
    int p0 = x * 32, c0 = y * 32;
    int lp = threadIdx.x & 31, lc = threadIdx.x >> 5;
    for (int cc = lc; cc < 32; cc += 8) {
      int c = c0 + cc, p = p0 + lp;
      t[cc][lp] = (c < C && p < P) ? in[((size_t)b*C + c)*P + p] : 0.f;
    }
    __syncthreads();
    for (int pp = lc; pp < 32; pp += 8) {
      int p = p0 + pp, c = c0 + lp;
      if (p < P && c < C) out[((size_t)b*P + p)*C + c] = t[lp][pp];
    }
  } else if (bid < 8610) {
    int wave = threadIdx.x >> 6, lane = threadIdx.x & 63;
    int row = (bid - 6144) * 4 + wave;
    const float* Ar = adj + (size_t)row * N_;
    int* cp = cols + (size_t)row * ELLW;
    unsigned long long below = (lane == 63) ? 0xFFFFFFFFFFFFFFFFull >> 1
                                            : ((1ull << lane) - 1ull);
    int base = 0;
    for (int i0 = 0; i0 < 20; i0++) {
      int j0 = i0 * 128 + lane * 2;
      float2 v = make_float2(0.f, 0.f);
      if (j0 + 1 < N_) v = *(const float2*)&Ar[j0];
      bool nz0 = (j0 < N_) && (v.x != 0.f);
      bool nz1 = (j0 + 1 < N_) && (v.y != 0.f);
      unsigned long long m0 = __ballot(nz0);
      unsigned long long m1 = __ballot(nz1);
      int pre = __popcll(m0 & below) + __popcll(m1 & below);
      int p0 = base + pre;
      int p1 = p0 + (nz0 ? 1 : 0);
      if (nz0 && p0 < ELLW) cp[p0] = j0;
      if (nz1 && p1 < ELLW) cp[p1] = j0 + 1;
      base += __popcll(m0) + __popcll(m1);
    }
    if (lane == 0) cnts[row] = (base > ELLW) ? ELLW : base;
  } else {
    // lin_w -> bf16 hi/lo in MFMA B-fragment order:
    // e = ((slab*8 + nt)*64 + lane)*8 + j ; k = slab*32 + (lane>>4)*8 + j ; n = nt*16 + (lane&15)
    int b = bid - 8610;                    // 0..479
    int e0 = (b * 256 + threadIdx.x) * 4;
    #pragma unroll
    for (int u = 0; u < 4; u++) {
      int e = e0 + u;
      int j = e & 7;
      int lane = (e >> 3) & 63;
      int nt = (e >> 9) & 7;
      int slab = e >> 12;
      int k = slab * 32 + ((lane >> 4) << 3) + j;
      int n = nt * 16 + (lane & 15);
      float x = lin_w[(size_t)k * 128 + n];
      unsigned short h = bf16_rne(x);
      whi[e] = h;
      wlo[e] = bf16_rne(x - bf16_back(h));
    }
  }
}

// ============ split-K vertex-align gather + bf16x3 MFMA GEMM ============
// M=128 per block: 4 waves x 2 m-tiles of 16 rows each -> each B-fragment load feeds 6 MFMAs.
__global__ __launch_bounds__(256) void k_align_mfma(
    const float* __restrict__ tr0, const float* __restrict__ tr1,
    const float* __restrict__ tr2, const float* __restrict__ tr3,
    const float* __restrict__ pos,
    const unsigned short* __restrict__ whi, const unsigned short* __restrict__ wlo,
    float* __restrict__ part, int kchunk) {
  int tid  = threadIdx.x;
  int wave = tid >> 6, lane = tid & 63;
  int q    = lane >> 4, l15 = lane & 15;
  int m0   = blockIdx.x * 128;
  int s    = blockIdx.y;

  float wgt[2][4]; int base[2][4];
  #pragma unroll
  for (int u = 0; u < 2; u++) {
    int mrow = m0 + (wave * 2 + u) * 16 + l15;
    int rowc = (mrow < R_) ? mrow : 0;
    int b = rowc / N_;
    float px = pos[rowc*3+0], py = pos[rowc*3+1], pz = pos[rowc*3+2];
    float hh = fminf(fmaxf(248.f*(py/pz)    + 111.5f, 0.f), 223.f);
    float wc = fminf(fmaxf(248.f*(px/(-pz)) + 111.5f, 0.f), 223.f);
    const int Sarr[4] = {56, 28, 14, 7};
    const int Carr[4] = {256, 512, 1024, 2048};
    #pragma unroll
    for (int sc = 0; sc < 4; sc++) {
      int S = Sarr[sc], C = Carr[sc];
      float dv = 224.f / (float)S;
      float x = hh / dv, y = wc / dv;
      int x1 = (int)floorf(x), y1 = (int)floorf(y);
      int x2 = min((int)ceilf(x), S - 1), y2 = min((int)ceilf(y), S - 1);
      float w = (float)((x2 - x1) * (y2 - y1));   // xi==x1,yi==y1 -> single tap
      if (mrow >= R_) w = 0.f;
      wgt[u][sc]  = w;
      base[u][sc] = (b * S * S + x1 * S + y1) * C;   // NHWC; add channel
    }
  }

  f32x4 acc[2][8];
  #pragma unroll
  for (int u = 0; u < 2; u++)
    #pragma unroll
    for (int nt = 0; nt < 8; nt++) acc[u][nt] = (f32x4){0.f, 0.f, 0.f, 0.f};

  const bf16x8* BH = (const bf16x8*)whi;
  const bf16x8* BL = (const bf16x8*)wlo;

  int kbeg = s * kchunk, kend = kbeg + kchunk;
  for (int k0 = kbeg; k0 < kend; k0 += 32) {
    const float* tr; int off, sI;
    if (k0 < 256)       { tr = tr0; off = 0;    sI = 0; }
    else if (k0 < 768)  { tr = tr1; off = 256;  sI = 1; }
    else if (k0 < 1792) { tr = tr2; off = 768;  sI = 2; }
    else                { tr = tr3; off = 1792; sI = 3; }

    bf16x8 ah[2], al[2];
    #pragma unroll
    for (int u = 0; u < 2; u++) {
      const float* src = tr + base[u][sI] + (k0 - off + q * 8);
      float4 a0 = *(const float4*)src;
      float4 a1 = *(const float4*)(src + 4);
      float wg = wgt[u][sI];
      float af[8] = {a0.x*wg, a0.y*wg, a0.z*wg, a0.w*wg,
                     a1.x*wg, a1.y*wg, a1.z*wg, a1.w*wg};
      #pragma unroll
      for (int j = 0; j < 8; j++) {
        unsigned short h = bf16_rne(af[j]);
        ah[u][j] = (short)h;
        al[u][j] = (short)bf16_rne(af[j] - bf16_back(h));
      }
    }

    int slab = k0 >> 5;
    bf16x8 Bh[8], Bl[8];
    #pragma unroll
    for (int nt = 0; nt < 8; nt++) {
      size_t fi = (size_t)(slab * 8 + nt) * 64 + lane;
      Bh[nt] = BH[fi];
      Bl[nt] = BL[fi];
    }
    // hi*hi + lo*hi + hi*lo (lo*lo dropped)
    #pragma unroll
    for (int nt = 0; nt < 8; nt++) {
      acc[0][nt] = __builtin_amdgcn_mfma_f32_16x16x32_bf16(ah[0], Bh[nt], acc[0][nt], 0, 0, 0);
      acc[1][nt] = __builtin_amdgcn_mfma_f32_16x16x32_bf16(ah[1], Bh[nt], acc[1][nt], 0, 0, 0);
    }
    #pragma unroll
    for (int nt = 0; nt < 8; nt++) {
      acc[0][nt] = __builtin_amdgcn_mfma_f32_16x16x32_bf16(al[0], Bh[nt], acc[0][nt], 0, 0, 0);
      acc[1][nt] = __builtin_amdgcn_mfma_f32_16x16x32_bf16(al[1], Bh[nt], acc[1][nt], 0, 0, 0);
    }
    #pragma unroll
    for (int nt = 0; nt < 8; nt++) {
      acc[0][nt] = __builtin_amdgcn_mfma_f32_16x16x32_bf16(ah[0], Bl[nt], acc[0][nt], 0, 0, 0);
      acc[1][nt] = __builtin_amdgcn_mfma_f32_16x16x32_bf16(ah[1], Bl[nt], acc[1][nt], 0, 0, 0);
    }
  }

  // C/D layout: col = lane&15, row_in_tile = q*4 + reg
  #pragma unroll
  for (int u = 0; u < 2; u++)
    #pragma unroll
    for (int nt = 0; nt < 8; nt++)
      #pragma unroll
      for (int r = 0; r < 4; r++) {
        int row = m0 + (wave * 2 + u) * 16 + q * 4 + r;
        if (row < R_)
          part[((size_t)s * R_ + row) * 128 + nt * 16 + l15] = acc[u][nt][r];
      }
}

// ============ fused X-build + GEMM ============
// MODE 0: X = [reduce(part)+lin_b | vf | pos] (K=259); MODE 1: X = relu(s + A@t) (K=128);
// MODE 2: X = skip + relu(s + A@t) (K=128). blockIdx.y = which; NW==3 && which==2 adds pb.
template<int MODE, int K, int NW>
__global__ __launch_bounds__(256) void k_fused(
    const float* __restrict__ part, const float* __restrict__ lin_b,
    const float* __restrict__ vf, const float* __restrict__ pos,
    const float* __restrict__ sin_, const float* __restrict__ tin,
    const float* skin,
    const int* __restrict__ cols, const int* __restrict__ cnts,
    const float* __restrict__ W0, const float* __restrict__ W1,
    const float* __restrict__ W2, const float* __restrict__ pb,
    float* __restrict__ o0, float* __restrict__ o1, float* o2,
    int nsplit) {
  constexpr int LDX = (K + 7) & ~3;       // 264 / 132 (keeps float4 alignment)
  __shared__ alignas(16) float X[32][LDX];
  __shared__ alignas(16) float Ws[32][128];
  int tid = threadIdx.x;
  int m0 = blockIdx.x * 32;
  int which = blockIdx.y;

  if (MODE == 0) {
    #pragma unroll 4
    for (int pass = 0; pass < 16; pass++) {
      int r = pass * 2 + (tid >> 7);
      int row = m0 + r;
      int k = tid & 127;
      if (row < R_) {
        float acc = lin_b[k];
        for (int ss = 0; ss < nsplit; ss++)
          acc += part[((size_t)ss * R_ + row) * 128 + k];
        X[r][k] = acc;
        X[r][128 + k] = vf[(size_t)row * 128 + k];
        if (k < 3) X[r][256 + k] = pos[(size_t)row * 3 + k];
      } else {
        X[r][k] = 0.f; X[r][128 + k] = 0.f;
        if (k < 3) X[r][256 + k] = 0.f;
      }
    }
  } else {
    int grp = tid >> 5, ln = tid & 31;
    #pragma unroll
    for (int pass = 0; pass < 4; pass++) {
      int r = pass * 8 + grp;
      int row = m0 + r;
      float4 acc = make_float4(0.f, 0.f, 0.f, 0.f);
      if (row < R_) {
        int b = row / N_;
        size_t tbase = (size_t)b * N_;
        acc = ((const float4*)sin_)[(size_t)row * 32 + ln];
        int cnt = cnts[row];
        const int* cp = cols + (size_t)row * ELLW;
        for (int i = 0; i < cnt; i++) {
          float4 vv = ((const float4*)tin)[(tbase + cp[i]) * 32 + ln];
          acc.x += vv.x; acc.y += vv.y; acc.z += vv.z; acc.w += vv.w;
        }
        acc.x = fmaxf(acc.x, 0.f); acc.y = fmaxf(acc.y, 0.f);
        acc.z = fmaxf(acc.z, 0.f); acc.w = fmaxf(acc.w, 0.f);
        if (MODE == 2) {
          float4 sk = ((const float4*)skin)[(size_t)row * 32 + ln];
          acc.x += sk.x; acc.y += sk.y; acc.z += sk.z; acc.w += sk.w;
        }
      }
      *(float4*)&X[r][ln * 4] = acc;
    }
  }
  __syncthreads();

  const float* W = (which == 0) ? W0 : (which == 1) ? W1 : W2;
  float* out     = (which == 0) ? o0 : (which == 1) ? o1 : o2;
  int cx = tid & 31, cy = tid >> 5;
  float acc[4][4];
  #pragma unroll
  for (int r = 0; r < 4; r++)
    #pragma unroll
    for (int c = 0; c < 4; c++) acc[r][c] = 0.f;

  for (int k0 = 0; k0 < K; k0 += 32) {
    #pragma unroll
    for (int i = 0; i < 4; i++) {
      int slot = tid + i * 256;
      int kk = slot >> 5, c4 = slot & 31;
      int k = k0 + kk;
      float4 v = make_float4(0.f, 0.f, 0.f, 0.f);
      if (k < K) v = *(const float4*)&W[(size_t)k * 128 + c4 * 4];
      *(float4*)&Ws[kk][c4 * 4] = v;
    }
    __syncthreads();
    int kmax = K - k0; if (kmax > 32) kmax = 32;
    for (int kk = 0; kk < kmax; kk++) {
      float av[4];
      #pragma unroll
      for (int r = 0; r < 4; r++) av[r] = X[cy * 4 + r][k0 + kk];   // FIXED: k0 + kk
      float4 bv = *(const float4*)&Ws[kk][cx * 4];
      float bb[4] = {bv.x, bv.y, bv.z, bv.w};
      #pragma unroll
      for (int r = 0; r < 4; r++)
        #pragma unroll
        for (int c = 0; c < 4; c++) acc[r][c] += av[r] * bb[c];
    }
    __syncthreads();
  }

  #pragma unroll
  for (int r = 0; r < 4; r++) {
    int row = m0 + cy * 4 + r;
    if (row < R_) {
      int col = cx * 4;
      float4 v;
      v.x = acc[r][0]; v.y = acc[r][1]; v.z = acc[r][2]; v.w = acc[r][3];
      if (NW == 3 && which == 2) {
        v.x += pb[col + 0]; v.y += pb[col + 1]; v.z += pb[col + 2]; v.w += pb[col + 3];
      }
      *(float4*)&out[(size_t)row * 128 + col] = v;
    }
  }
}

// ---------------- last spmm2 + fused 128->3 GEMV (both gf weights) ----------------
__global__ __launch_bounds__(256) void k_spmm_gf(
    const float* __restrict__ u, const float* __restrict__ v,
    const int* __restrict__ cols, const int* __restrict__ cnts,
    const float* __restrict__ skipb,
    const float* __restrict__ gw0, const float* __restrict__ gw1,
    float* __restrict__ gsb, float* __restrict__ gtb) {
  int tid = threadIdx.x;
  int grp = tid >> 5, ln = tid & 31;
  int row = blockIdx.x * 8 + grp;           // 1233*8 = 9864
  int b = row / N_;
  size_t tbase = (size_t)b * N_;
  float4 acc = ((const float4*)u)[(size_t)row*32 + ln];
  int cnt = cnts[row];
  const int* cp = cols + (size_t)row * ELLW;
  for (int i = 0; i < cnt; i++) {
    float4 vv = ((const float4*)v)[(tbase + cp[i])*32 + ln];
    acc.x += vv.x; acc.y += vv.y; acc.z += vv.z; acc.w += vv.w;
  }
  acc.x = fmaxf(acc.x, 0.f); acc.y = fmaxf(acc.y, 0.f);
  acc.z = fmaxf(acc.z, 0.f); acc.w = fmaxf(acc.w, 0.f);
  float4 sk = ((const float4*)skipb)[(size_t)row*32 + ln];
  acc.x += sk.x; acc.y += sk.y; acc.z += sk.z; acc.w += sk.w;
  float av[4] = {acc.x, acc.y, acc.z, acc.w};
  int j0 = ln * 4;
  float p0 = 0.f, p1 = 0.f, p2 = 0.f, q0 = 0.f, q1 = 0.f, q2 = 0.f;
  #pragma unroll
  for (int uu = 0; uu < 4; uu++) {
    int j = j0 + uu;
    p0 += av[uu] * gw0[j*3+0]; p1 += av[uu] * gw0[j*3+1]; p2 += av[uu] * gw0[j*3+2];
    q0 += av[uu] * gw1[j*3+0]; q1 += av[uu] * gw1[j*3+1]; q2 += av[uu] * gw1[j*3+2];
  }
  #pragma unroll
  for (int off = 16; off >= 1; off >>= 1) {
    p0 += __shfl_xor(p0, off); p1 += __shfl_xor(p1, off); p2 += __shfl_xor(p2, off);
    q0 += __shfl_xor(q0, off); q1 += __shfl_xor(q1, off); q2 += __shfl_xor(q2, off);
  }
  if (ln == 0) {
    gsb[(size_t)row*128 + 0] = p0; gsb[(size_t)row*128 + 1] = p1; gsb[(size_t)row*128 + 2] = p2;
    gtb[(size_t)row*128 + 0] = q0; gtb[(size_t)row*128 + 1] = q1; gtb[(size_t)row*128 + 2] = q2;
  }
}

// ---------------- final: out = pos + tanh(relu(s + A@t)) ----------------
__global__ __launch_bounds__(256) void k_gf_final(
    const float* __restrict__ sb, const float* __restrict__ tb,
    const int* __restrict__ cols, const int* __restrict__ cnts,
    const float* __restrict__ pos, float* __restrict__ out) {
  int wave = threadIdx.x >> 6, lane = threadIdx.x & 63;
  int row = blockIdx.x * 4 + wave;          // grid 2466
  if (lane >= 3) return;
  int b = row / N_;
  float acc = sb[(size_t)row*128 + lane];
  int cnt = cnts[row];
  const int* cp = cols + (size_t)row * ELLW;
  size_t tbase = (size_t)b * N_;
  for (int i = 0; i < cnt; i++)
    acc += tb[(tbase + cp[i])*128 + lane];
  float v = tanhf(fmaxf(acc, 0.f));
  out[(size_t)row*3 + lane] = pos[(size_t)row*3 + lane] + v;
}

extern "C" void kernel_launch(void* const* d_in, const int* in_sizes, int n_in,
                              void* d_out, int out_size, void* d_ws, size_t ws_size,
                              hipStream_t stream) {
  const float* conv2_3 = (const float*)d_in[0];
  const float* conv3_4 = (const float*)d_in[1];
  const float* conv4_6 = (const float*)d_in[2];
  const float* conv5_3 = (const float*)d_in[3];
  const float* pos     = (const float*)d_in[4];
  const float* vf      = (const float*)d_in[5];
  const float* adj     = (const float*)d_in[6];
  const float* lin_w   = (const float*)d_in[7];
  const float* lin_b   = (const float*)d_in[8];
  const float* r_pw[3]  = {(const float*)d_in[9],  (const float*)d_in[15], (const float*)d_in[21]};
  const float* r_pb[3]  = {(const float*)d_in[10], (const float*)d_in[16], (const float*)d_in[22]};
  const float* r_w00[3] = {(const float*)d_in[11], (const float*)d_in[17], (const float*)d_in[23]};
  const float* r_w01[3] = {(const float*)d_in[12], (const float*)d_in[18], (const float*)d_in[24]};
  const float* r_w10[3] = {(const float*)d_in[13], (const float*)d_in[19], (const float*)d_in[25]};
  const float* r_w11[3] = {(const float*)d_in[14], (const float*)d_in[20], (const float*)d_in[26]};
  const float* gf_w0 = (const float*)d_in[27];
  const float* gf_w1 = (const float*)d_in[28];
  float* out = (float*)d_out;

  // ---- workspace layout (float slots) ----
  const size_t TR_TOT = (size_t)4*(256*3136 + 512*784 + 1024*196 + 2048*49); // 6,021,120
  const size_t ELL_I  = (size_t)R_ * (ELLW + 1);                             //   956,808
  const size_t ROWF   = (size_t)R_ * 128;                                    // 1,262,592
  const size_t WS_E   = 491520;                                              // bf16 elems per array

  float* ws  = (float*)d_ws;
  float* tr0 = ws;
  float* tr1 = tr0 + (size_t)4*256*3136;
  float* tr2 = tr1 + (size_t)4*512*784;
  float* tr3 = tr2 + (size_t)4*1024*196;
  int*   ell_cnt  = (int*)(tr3 + (size_t)4*2048*49);
  int*   ell_cols = ell_cnt + R_;
  unsigned short* whi = (unsigned short*)(ell_cols + (size_t)R_*ELLW);
  unsigned short* wlo = whi + WS_E;
  float* part = (float*)(wlo + WS_E);

  size_t fixed_f = TR_TOT + ELL_I + WS_E/2 + WS_E/2;   // tr + ell + whi/wlo (as float slots)
  size_t need8 = (fixed_f + (size_t)13 * ROWF) * sizeof(float);
  int nsplit = (ws_size >= need8) ? 8 : 4;
  int kchunk = 3840 / nsplit;

  float* s_   = part + (size_t)nsplit * ROWF;
  float* t_   = s_   + ROWF;
  float* u_   = t_   + ROWF;
  float* v_   = u_   + ROWF;
  float* skip = v_   + ROWF;
  float* gsb  = part;            // part is dead after the mode-0 k_fused
  float* gtb  = part + ROWF;

  // D0: transposes + ELL + W split
  k_pre<<<9090, 256, 0, stream>>>(conv2_3, conv3_4, conv4_6, conv5_3,
                                  tr0, tr1, tr2, tr3,
                                  adj, ell_cols, ell_cnt,
                                  lin_w, whi, wlo);

  // D1: split-K MFMA align GEMM (M=128 blocks)
  k_align_mfma<<<dim3(78, nsplit), 256, 0, stream>>>(tr0, tr1, tr2, tr3, pos,
                                                     whi, wlo, part, kchunk);

  // D2: reduce+concat -> gemm3 {w00,w01,pw}+pb  => s,t,skip
  k_fused<0,259,3><<<dim3(309,3), 256, 0, stream>>>(
      part, lin_b, vf, pos, nullptr, nullptr, nullptr, nullptr, nullptr,
      r_w00[0], r_w01[0], r_pw[0], r_pb[0], s_, t_, skip, nsplit);

  for (int rb = 0; rb < 3; rb++) {
    // spmm -> gemm2 {w10,w11}  => u,v
    k_fused<1,128,2><<<dim3(309,2), 256, 0, stream>>>(
        nullptr, nullptr, nullptr, nullptr, s_, t_, nullptr, ell_cols, ell_cnt,
        r_w10[rb], r_w11[rb], nullptr, nullptr, u_, v_, nullptr, 0);
    if (rb < 2) {
      // spmm2(+skip) -> gemm3 {w00',w01',pw'}+pb'  => s,t,skip
      k_fused<2,128,3><<<dim3(309,3), 256, 0, stream>>>(
          nullptr, nullptr, nullptr, nullptr, u_, v_, skip, ell_cols, ell_cnt,
          r_w00[rb+1], r_w01[rb+1], r_pw[rb+1], r_pb[rb+1], s_, t_, skip, 0);
    } else {
      // spmm2(+skip) -> fused 128->3 gemv  => gsb,gtb
      k_spmm_gf<<<1233, 256, 0, stream>>>(u_, v_, ell_cols, ell_cnt, skip,
                                          gf_w0, gf_w1, gsb, gtb);
    }
  }

  // D9: out = pos + tanh(relu(gsb + A@gtb))
  k_gf_final<<<2466, 256, 0, stream>>>(gsb, gtb, ell_cols, ell_cnt, pos, out);
}

// Round 8
// 2332.499 us; speedup vs baseline: 1.0653x; 1.0653x over previous
//
#include <hip/hip_runtime.h>
#include <cmath>

#define B_   4
#define N_   2466
#define R_   (B_*N_)     // 9864
#define ELLW 96

typedef __attribute__((ext_vector_type(8))) short bf16x8;
typedef __attribute__((ext_vector_type(4))) float f32x4;

__device__ __forceinline__ unsigned short bf16_rne(float x) {
  union { float f; unsigned u; } c; c.f = x;
  unsigned r = c.u + 0x7FFFu + ((c.u >> 16) & 1u);
  return (unsigned short)(r >> 16);
}
__device__ __forceinline__ float bf16_back(unsigned short h) {
  union { float f; unsigned u; } c; c.u = ((unsigned)h) << 16;
  return c.f;
}

// ============ fused pre-kernel: transposes + ELL + W hi/lo fragment split ============
__global__ __launch_bounds__(256) void k_pre(
    const float* __restrict__ c2, const float* __restrict__ c3,
    const float* __restrict__ c4, const float* __restrict__ c5,
    float* __restrict__ t0, float* __restrict__ t1,
    float* __restrict__ t2, float* __restrict__ t3,
    const float* __restrict__ adj, int* __restrict__ cols, int* __restrict__ cnts,
    const float* __restrict__ lin_w,
    unsigned short* __restrict__ whi, unsigned short* __restrict__ wlo) {
  __shared__ float t[32][33];
  int bid = blockIdx.x;
  if (bid < 6144) {
    const float* in; float* out; int C, P, nx, ny, rem;
    if (bid < 3136)      { in = c2; out = t0; C = 256;  P = 3136; nx = 98; ny = 8;  rem = bid; }
    else if (bid < 4736) { in = c3; out = t1; C = 512;  P = 784;  nx = 25; ny = 16; rem = bid - 3136; }
    else if (bid < 5632) { in = c4; out = t2; C = 1024; P = 196;  nx = 7;  ny = 32; rem = bid - 4736; }
    else                 { in = c5; out = t3; C = 2048; P = 49;   nx = 2;  ny = 64; rem = bid - 5632; }
    int x = rem % nx; int tq = rem / nx; int y = tq % ny; int b = tq / ny;
    int p0 = x * 32, c0 = y * 32;
    int lp = threadIdx.x & 31, lc = threadIdx.x >> 5;
    for (int cc = lc; cc < 32; cc += 8) {
      int c = c0 + cc, p = p0 + lp;
      t[cc][lp] = (c < C && p < P) ? in[((size_t)b*C + c)*P + p] : 0.f;
    }
    __syncthreads();
    for (int pp = lc; pp < 32; pp += 8) {
      int p = p0 + pp, c = c0 + lp;
      if (p < P && c < C) out[((size_t)b*P + p)*C + c] = t[lp][pp];
    }
  } else if (bid < 8610) {
    int wave = threadIdx.x >> 6, lane = threadIdx.x & 63;
    int row = (bid - 6144) * 4 + wave;
    const float* Ar = adj + (size_t)row * N_;
    int* cp = cols + (size_t)row * ELLW;
    unsigned long long below = (lane == 63) ? 0xFFFFFFFFFFFFFFFFull >> 1
                                            : ((1ull << lane) - 1ull);
    int base = 0;
    for (int i0 = 0; i0 < 20; i0++) {
      int j0 = i0 * 128 + lane * 2;
      float2 v = make_float2(0.f, 0.f);
      if (j0 + 1 < N_) v = *(const float2*)&Ar[j0];
      bool nz0 = (j0 < N_) && (v.x != 0.f);
      bool nz1 = (j0 + 1 < N_) && (v.y != 0.f);
      unsigned long long m0 = __ballot(nz0);
      unsigned long long m1 = __ballot(nz1);
      int pre = __popcll(m0 & below) + __popcll(m1 & below);
      int p0 = base + pre;
      int p1 = p0 + (nz0 ? 1 : 0);
      if (nz0 && p0 < ELLW) cp[p0] = j0;
      if (nz1 && p1 < ELLW) cp[p1] = j0 + 1;
      base += __popcll(m0) + __popcll(m1);
    }
    if (lane == 0) cnts[row] = (base > ELLW) ? ELLW : base;
  } else {
    // lin_w -> bf16 hi/lo in MFMA B-fragment order:
    // e = ((slab*8 + nt)*64 + lane)*8 + j ; k = slab*32 + (lane>>4)*8 + j ; n = nt*16 + (lane&15)
    int b = bid - 8610;                    // 0..479
    int e0 = (b * 256 + threadIdx.x) * 4;
    #pragma unroll
    for (int u = 0; u < 4; u++) {
      int e = e0 + u;
      int j = e & 7;
      int lane = (e >> 3) & 63;
      int nt = (e >> 9) & 7;
      int slab = e >> 12;
      int k = slab * 32 + ((lane >> 4) << 3) + j;
      int n = nt * 16 + (lane & 15);
      float x = lin_w[(size_t)k * 128 + n];
      unsigned short h = bf16_rne(x);
      whi[e] = h;
      wlo[e] = bf16_rne(x - bf16_back(h));
    }
  }
}

// ============ split-K vertex-align gather + bf16x3 MFMA GEMM ============
// M=128 per block: 4 waves x 2 m-tiles of 16 rows each.
__global__ __launch_bounds__(256) void k_align_mfma(
    const float* __restrict__ tr0, const float* __restrict__ tr1,
    const float* __restrict__ tr2, const float* __restrict__ tr3,
    const float* __restrict__ pos,
    const unsigned short* __restrict__ whi, const unsigned short* __restrict__ wlo,
    float* __restrict__ part, int kchunk) {
  int tid  = threadIdx.x;
  int wave = tid >> 6, lane = tid & 63;
  int q    = lane >> 4, l15 = lane & 15;
  int m0   = blockIdx.x * 128;
  int s    = blockIdx.y;

  float wgt[2][4]; int base[2][4];
  #pragma unroll
  for (int u = 0; u < 2; u++) {
    int mrow = m0 + (wave * 2 + u) * 16 + l15;
    int rowc = (mrow < R_) ? mrow : 0;
    int b = rowc / N_;
    float px = pos[rowc*3+0], py = pos[rowc*3+1], pz = pos[rowc*3+2];
    float hh = fminf(fmaxf(248.f*(py/pz)    + 111.5f, 0.f), 223.f);
    float wc = fminf(fmaxf(248.f*(px/(-pz)) + 111.5f, 0.f), 223.f);
    const int Sarr[4] = {56, 28, 14, 7};
    const int Carr[4] = {256, 512, 1024, 2048};
    #pragma unroll
    for (int sc = 0; sc < 4; sc++) {
      int S = Sarr[sc], C = Carr[sc];
      float dv = 224.f / (float)S;
      float x = hh / dv, y = wc / dv;
      int x1 = (int)floorf(x), y1 = (int)floorf(y);
      int x2 = min((int)ceilf(x), S - 1), y2 = min((int)ceilf(y), S - 1);
      float w = (float)((x2 - x1) * (y2 - y1));   // xi==x1,yi==y1 -> single tap
      if (mrow >= R_) w = 0.f;
      wgt[u][sc]  = w;
      base[u][sc] = (b * S * S + x1 * S + y1) * C;   // NHWC; add channel
    }
  }

  f32x4 acc[2][8];
  #pragma unroll
  for (int u = 0; u < 2; u++)
    #pragma unroll
    for (int nt = 0; nt < 8; nt++) acc[u][nt] = (f32x4){0.f, 0.f, 0.f, 0.f};

  const bf16x8* BH = (const bf16x8*)whi;
  const bf16x8* BL = (const bf16x8*)wlo;

  int kbeg = s * kchunk, kend = kbeg + kchunk;
  for (int k0 = kbeg; k0 < kend; k0 += 32) {
    const float* tr; int off, sI;
    if (k0 < 256)       { tr = tr0; off = 0;    sI = 0; }
    else if (k0 < 768)  { tr = tr1; off = 256;  sI = 1; }
    else if (k0 < 1792) { tr = tr2; off = 768;  sI = 2; }
    else                { tr = tr3; off = 1792; sI = 3; }

    bf16x8 ah[2], al[2];
    #pragma unroll
    for (int u = 0; u < 2; u++) {
      const float* src = tr + base[u][sI] + (k0 - off + q * 8);
      float4 a0 = *(const float4*)src;
      float4 a1 = *(const float4*)(src + 4);
      float wg = wgt[u][sI];
      float af[8] = {a0.x*wg, a0.y*wg, a0.z*wg, a0.w*wg,
                     a1.x*wg, a1.y*wg, a1.z*wg, a1.w*wg};
      #pragma unroll
      for (int j = 0; j < 8; j++) {
        unsigned short h = bf16_rne(af[j]);
        ah[u][j] = (short)h;
        al[u][j] = (short)bf16_rne(af[j] - bf16_back(h));
      }
    }

    int slab = k0 >> 5;
    bf16x8 Bh[8], Bl[8];
    #pragma unroll
    for (int nt = 0; nt < 8; nt++) {
      size_t fi = (size_t)(slab * 8 + nt) * 64 + lane;
      Bh[nt] = BH[fi];
      Bl[nt] = BL[fi];
    }
    // hi*hi + lo*hi + hi*lo (lo*lo dropped)
    #pragma unroll
    for (int nt = 0; nt < 8; nt++) {
      acc[0][nt] = __builtin_amdgcn_mfma_f32_16x16x32_bf16(ah[0], Bh[nt], acc[0][nt], 0, 0, 0);
      acc[1][nt] = __builtin_amdgcn_mfma_f32_16x16x32_bf16(ah[1], Bh[nt], acc[1][nt], 0, 0, 0);
    }
    #pragma unroll
    for (int nt = 0; nt < 8; nt++) {
      acc[0][nt] = __builtin_amdgcn_mfma_f32_16x16x32_bf16(al[0], Bh[nt], acc[0][nt], 0, 0, 0);
      acc[1][nt] = __builtin_amdgcn_mfma_f32_16x16x32_bf16(al[1], Bh[nt], acc[1][nt], 0, 0, 0);
    }
    #pragma unroll
    for (int nt = 0; nt < 8; nt++) {
      acc[0][nt] = __builtin_amdgcn_mfma_f32_16x16x32_bf16(ah[0], Bl[nt], acc[0][nt], 0, 0, 0);
      acc[1][nt] = __builtin_amdgcn_mfma_f32_16x16x32_bf16(ah[1], Bl[nt], acc[1][nt], 0, 0, 0);
    }
  }

  // C/D layout: col = lane&15, row_in_tile = q*4 + reg
  #pragma unroll
  for (int u = 0; u < 2; u++)
    #pragma unroll
    for (int nt = 0; nt < 8; nt++)
      #pragma unroll
      for (int r = 0; r < 4; r++) {
        int row = m0 + (wave * 2 + u) * 16 + q * 4 + r;
        if (row < R_)
          part[((size_t)s * R_ + row) * 128 + nt * 16 + l15] = acc[u][nt][r];
      }
}

// ============ fused X-build + GEMM ============
// MODE 0: X = [reduce(part)+lin_b | vf | pos] (K=259); MODE 1: X = relu(s + A@t) (K=128);
// MODE 2: X = skip + relu(s + A@t) (K=128). blockIdx.y = which; NW==3 && which==2 adds pb.
template<int MODE, int K, int NW>
__global__ __launch_bounds__(256) void k_fused(
    const float* __restrict__ part, const float* __restrict__ lin_b,
    const float* __restrict__ vf, const float* __restrict__ pos,
    const float* __restrict__ sin_, const float* __restrict__ tin,
    const float* __restrict__ skin,
    const int* __restrict__ cols, const int* __restrict__ cnts,
    const float* __restrict__ W0, const float* __restrict__ W1,
    const float* __restrict__ W2, const float* __restrict__ pb,
    float* __restrict__ o0, float* __restrict__ o1, float* __restrict__ o2,
    int nsplit) {
  constexpr int LDX = (K + 7) & ~3;       // 264 / 132 (16B-aligned row stride)
  __shared__ alignas(16) float X[32][LDX];
  __shared__ alignas(16) float Ws[32][128];
  int tid = threadIdx.x;
  int m0 = blockIdx.x * 32;
  int which = blockIdx.y;
  int grp = tid >> 5, ln = tid & 31;

  if (MODE == 0) {
    // flat float4 build: thread (grp,ln) owns one float4 of one row per pass.
    // No unroll pragma: keep live-register count tiny (R7's unroll-4 spilled to 1.5 GB scratch).
    for (int pass = 0; pass < 4; pass++) {
      int r = pass * 8 + grp;
      int row = m0 + r;
      if (row < R_) {
        float4 a4 = ((const float4*)lin_b)[ln];
        for (int ss = 0; ss < nsplit; ss++) {
          float4 pv = ((const float4*)part)[((size_t)ss * R_ + row) * 32 + ln];
          a4.x += pv.x; a4.y += pv.y; a4.z += pv.z; a4.w += pv.w;
        }
        *(float4*)&X[r][ln * 4] = a4;
        *(float4*)&X[r][128 + ln * 4] = ((const float4*)vf)[(size_t)row * 32 + ln];
        if (ln < 3) X[r][256 + ln] = pos[(size_t)row * 3 + ln];
      } else {
        *(float4*)&X[r][ln * 4] = make_float4(0.f, 0.f, 0.f, 0.f);
        *(float4*)&X[r][128 + ln * 4] = make_float4(0.f, 0.f, 0.f, 0.f);
        if (ln < 3) X[r][256 + ln] = 0.f;
      }
    }
  } else {
    for (int pass = 0; pass < 4; pass++) {
      int r = pass * 8 + grp;
      int row = m0 + r;
      float4 acc = make_float4(0.f, 0.f, 0.f, 0.f);
      if (row < R_) {
        int b = row / N_;
        size_t tbase = (size_t)b * N_;
        acc = ((const float4*)sin_)[(size_t)row * 32 + ln];
        int cnt = cnts[row];
        const int* cp = cols + (size_t)row * ELLW;
        for (int i = 0; i < cnt; i++) {
          float4 vv = ((const float4*)tin)[(tbase + cp[i]) * 32 + ln];
          acc.x += vv.x; acc.y += vv.y; acc.z += vv.z; acc.w += vv.w;
        }
        acc.x = fmaxf(acc.x, 0.f); acc.y = fmaxf(acc.y, 0.f);
        acc.z = fmaxf(acc.z, 0.f); acc.w = fmaxf(acc.w, 0.f);
        if (MODE == 2) {
          float4 sk = ((const float4*)skin)[(size_t)row * 32 + ln];
          acc.x += sk.x; acc.y += sk.y; acc.z += sk.z; acc.w += sk.w;
        }
      }
      *(float4*)&X[r][ln * 4] = acc;
    }
  }
  __syncthreads();

  const float* W = (which == 0) ? W0 : (which == 1) ? W1 : W2;
  float* out     = (which == 0) ? o0 : (which == 1) ? o1 : o2;
  int cx = tid & 31, cy = tid >> 5;
  float acc[4][4];
  #pragma unroll
  for (int r = 0; r < 4; r++)
    #pragma unroll
    for (int c = 0; c < 4; c++) acc[r][c] = 0.f;

  for (int k0 = 0; k0 < K; k0 += 32) {
    #pragma unroll
    for (int i = 0; i < 4; i++) {
      int slot = tid + i * 256;
      int kk = slot >> 5, c4 = slot & 31;
      int k = k0 + kk;
      float4 v = make_float4(0.f, 0.f, 0.f, 0.f);
      if (k < K) v = *(const float4*)&W[(size_t)k * 128 + c4 * 4];
      *(float4*)&Ws[kk][c4 * 4] = v;
    }
    __syncthreads();
    int kmax = K - k0; if (kmax > 32) kmax = 32;
    for (int kk = 0; kk < kmax; kk++) {
      float av[4];
      #pragma unroll
      for (int r = 0; r < 4; r++) av[r] = X[cy * 4 + r][k0 + kk];
      float4 bv = *(const float4*)&Ws[kk][cx * 4];
      float bb[4] = {bv.x, bv.y, bv.z, bv.w};
      #pragma unroll
      for (int r = 0; r < 4; r++)
        #pragma unroll
        for (int c = 0; c < 4; c++) acc[r][c] += av[r] * bb[c];
    }
    __syncthreads();
  }

  #pragma unroll
  for (int r = 0; r < 4; r++) {
    int row = m0 + cy * 4 + r;
    if (row < R_) {
      int col = cx * 4;
      float4 v;
      v.x = acc[r][0]; v.y = acc[r][1]; v.z = acc[r][2]; v.w = acc[r][3];
      if (NW == 3 && which == 2) {
        v.x += pb[col + 0]; v.y += pb[col + 1]; v.z += pb[col + 2]; v.w += pb[col + 3];
      }
      *(float4*)&out[(size_t)row * 128 + col] = v;
    }
  }
}

// ---------------- last spmm2 + fused 128->3 GEMV (both gf weights) ----------------
__global__ __launch_bounds__(256) void k_spmm_gf(
    const float* __restrict__ u, const float* __restrict__ v,
    const int* __restrict__ cols, const int* __restrict__ cnts,
    const float* __restrict__ skipb,
    const float* __restrict__ gw0, const float* __restrict__ gw1,
    float* __restrict__ gsb, float* __restrict__ gtb) {
  int tid = threadIdx.x;
  int grp = tid >> 5, ln = tid & 31;
  int row = blockIdx.x * 8 + grp;           // 1233*8 = 9864
  int b = row / N_;
  size_t tbase = (size_t)b * N_;
  float4 acc = ((const float4*)u)[(size_t)row*32 + ln];
  int cnt = cnts[row];
  const int* cp = cols + (size_t)row * ELLW;
  for (int i = 0; i < cnt; i++) {
    float4 vv = ((const float4*)v)[(tbase + cp[i])*32 + ln];
    acc.x += vv.x; acc.y += vv.y; acc.z += vv.z; acc.w += vv.w;
  }
  acc.x = fmaxf(acc.x, 0.f); acc.y = fmaxf(acc.y, 0.f);
  acc.z = fmaxf(acc.z, 0.f); acc.w = fmaxf(acc.w, 0.f);
  float4 sk = ((const float4*)skipb)[(size_t)row*32 + ln];
  acc.x += sk.x; acc.y += sk.y; acc.z += sk.z; acc.w += sk.w;
  float av[4] = {acc.x, acc.y, acc.z, acc.w};
  int j0 = ln * 4;
  float p0 = 0.f, p1 = 0.f, p2 = 0.f, q0 = 0.f, q1 = 0.f, q2 = 0.f;
  #pragma unroll
  for (int uu = 0; uu < 4; uu++) {
    int j = j0 + uu;
    p0 += av[uu] * gw0[j*3+0]; p1 += av[uu] * gw0[j*3+1]; p2 += av[uu] * gw0[j*3+2];
    q0 += av[uu] * gw1[j*3+0]; q1 += av[uu] * gw1[j*3+1]; q2 += av[uu] * gw1[j*3+2];
  }
  #pragma unroll
  for (int off = 16; off >= 1; off >>= 1) {
    p0 += __shfl_xor(p0, off); p1 += __shfl_xor(p1, off); p2 += __shfl_xor(p2, off);
    q0 += __shfl_xor(q0, off); q1 += __shfl_xor(q1, off); q2 += __shfl_xor(q2, off);
  }
  if (ln == 0) {
    gsb[(size_t)row*128 + 0] = p0; gsb[(size_t)row*128 + 1] = p1; gsb[(size_t)row*128 + 2] = p2;
    gtb[(size_t)row*128 + 0] = q0; gtb[(size_t)row*128 + 1] = q1; gtb[(size_t)row*128 + 2] = q2;
  }
}

// ---------------- final: out = pos + tanh(relu(s + A@t)) ----------------
__global__ __launch_bounds__(256) void k_gf_final(
    const float* __restrict__ sb, const float* __restrict__ tb,
    const int* __restrict__ cols, const int* __restrict__ cnts,
    const float* __restrict__ pos, float* __restrict__ out) {
  int wave = threadIdx.x >> 6, lane = threadIdx.x & 63;
  int row = blockIdx.x * 4 + wave;          // grid 2466
  if (lane >= 3) return;
  int b = row / N_;
  float acc = sb[(size_t)row*128 + lane];
  int cnt = cnts[row];
  const int* cp = cols + (size_t)row * ELLW;
  size_t tbase = (size_t)b * N_;
  for (int i = 0; i < cnt; i++)
    acc += tb[(tbase + cp[i])*128 + lane];
  float v = tanhf(fmaxf(acc, 0.f));
  out[(size_t)row*3 + lane] = pos[(size_t)row*3 + lane] + v;
}

extern "C" void kernel_launch(void* const* d_in, const int* in_sizes, int n_in,
                              void* d_out, int out_size, void* d_ws, size_t ws_size,
                              hipStream_t stream) {
  const float* conv2_3 = (const float*)d_in[0];
  const float* conv3_4 = (const float*)d_in[1];
  const float* conv4_6 = (const float*)d_in[2];
  const float* conv5_3 = (const float*)d_in[3];
  const float* pos     = (const float*)d_in[4];
  const float* vf      = (const float*)d_in[5];
  const float* adj     = (const float*)d_in[6];
  const float* lin_w   = (const float*)d_in[7];
  const float* lin_b   = (const float*)d_in[8];
  const float* r_pw[3]  = {(const float*)d_in[9],  (const float*)d_in[15], (const float*)d_in[21]};
  const float* r_pb[3]  = {(const float*)d_in[10], (const float*)d_in[16], (const float*)d_in[22]};
  const float* r_w00[3] = {(const float*)d_in[11], (const float*)d_in[17], (const float*)d_in[23]};
  const float* r_w01[3] = {(const float*)d_in[12], (const float*)d_in[18], (const float*)d_in[24]};
  const float* r_w10[3] = {(const float*)d_in[13], (const float*)d_in[19], (const float*)d_in[25]};
  const float* r_w11[3] = {(const float*)d_in[14], (const float*)d_in[20], (const float*)d_in[26]};
  const float* gf_w0 = (const float*)d_in[27];
  const float* gf_w1 = (const float*)d_in[28];
  float* out = (float*)d_out;

  // ---- workspace layout (float slots) ----
  const size_t TR_TOT = (size_t)4*(256*3136 + 512*784 + 1024*196 + 2048*49); // 6,021,120
  const size_t ELL_I  = (size_t)R_ * (ELLW + 1);                             //   956,808
  const size_t ROWF   = (size_t)R_ * 128;                                    // 1,262,592
  const size_t WS_E   = 491520;                                              // bf16 elems per array

  float* ws  = (float*)d_ws;
  float* tr0 = ws;
  float* tr1 = tr0 + (size_t)4*256*3136;
  float* tr2 = tr1 + (size_t)4*512*784;
  float* tr3 = tr2 + (size_t)4*1024*196;
  int*   ell_cnt  = (int*)(tr3 + (size_t)4*2048*49);
  int*   ell_cols = ell_cnt + R_;
  unsigned short* whi = (unsigned short*)(ell_cols + (size_t)R_*ELLW);
  unsigned short* wlo = whi + WS_E;
  float* part = (float*)(wlo + WS_E);

  size_t fixed_f = TR_TOT + ELL_I + WS_E/2 + WS_E/2;   // tr + ell + whi/wlo (as float slots)
  size_t need8 = (fixed_f + (size_t)13 * ROWF) * sizeof(float);
  int nsplit = (ws_size >= need8) ? 8 : 4;
  int kchunk = 3840 / nsplit;

  float* s_   = part + (size_t)nsplit * ROWF;
  float* t_   = s_   + ROWF;
  float* u_   = t_   + ROWF;
  float* v_   = u_   + ROWF;
  float* skip = v_   + ROWF;
  float* gsb  = part;            // part is dead after the mode-0 k_fused
  float* gtb  = part + ROWF;

  // D0: transposes + ELL + W split
  k_pre<<<9090, 256, 0, stream>>>(conv2_3, conv3_4, conv4_6, conv5_3,
                                  tr0, tr1, tr2, tr3,
                                  adj, ell_cols, ell_cnt,
                                  lin_w, whi, wlo);

  // D1: split-K MFMA align GEMM (M=128 blocks)
  k_align_mfma<<<dim3(78, nsplit), 256, 0, stream>>>(tr0, tr1, tr2, tr3, pos,
                                                     whi, wlo, part, kchunk);

  // D2: reduce+concat -> gemm3 {w00,w01,pw}+pb  => s,t,skip
  k_fused<0,259,3><<<dim3(309,3), 256, 0, stream>>>(
      part, lin_b, vf, pos, nullptr, nullptr, nullptr, nullptr, nullptr,
      r_w00[0], r_w01[0], r_pw[0], r_pb[0], s_, t_, skip, nsplit);

  for (int rb = 0; rb < 3; rb++) {
    // spmm -> gemm2 {w10,w11}  => u,v
    k_fused<1,128,2><<<dim3(309,2), 256, 0, stream>>>(
        nullptr, nullptr, nullptr, nullptr, s_, t_, nullptr, ell_cols, ell_cnt,
        r_w10[rb], r_w11[rb], nullptr, nullptr, u_, v_, nullptr, 0);
    if (rb < 2) {
      // spmm2(+skip) -> gemm3 {w00',w01',pw'}+pb'  => s,t,skip
      k_fused<2,128,3><<<dim3(309,3), 256, 0, stream>>>(
          nullptr, nullptr, nullptr, nullptr, u_, v_, skip, ell_cols, ell_cnt,
          r_w00[rb+1], r_w01[rb+1], r_pw[rb+1], r_pb[rb+1], s_, t_, skip, 0);
    } else {
      // spmm2(+skip) -> fused 128->3 gemv  => gsb,gtb
      k_spmm_gf<<<1233, 256, 0, stream>>>(u_, v_, ell_cols, ell_cnt, skip,
                                          gf_w0, gf_w1, gsb, gtb);
    }
  }

  // D9: out = pos + tanh(relu(gsb + A@gtb))
  k_gf_final<<<2466, 256, 0, stream>>>(gsb, gtb, ell_cols, ell_cnt, pos, out);
}

// Round 9
// 651.076 us; speedup vs baseline: 3.8165x; 3.5825x over previous
//
#include <hip/hip_runtime.h>
#include <cmath>

#define B_   4
#define N_   2466
#define R_   (B_*N_)     // 9864
#define ELLW 96

typedef __attribute__((ext_vector_type(8))) short bf16x8;
typedef __attribute__((ext_vector_type(4))) float f32x4;

__device__ __forceinline__ unsigned short bf16_rne(float x) {
  union { float f; unsigned u; } c; c.f = x;
  unsigned r = c.u + 0x7FFFu + ((c.u >> 16) & 1u);
  return (unsigned short)(r >> 16);
}
__device__ __forceinline__ float bf16_back(unsigned short h) {
  union { float f; unsigned u; } c; c.u = ((unsigned)h) << 16;
  return c.f;
}

// ============ fused pre-kernel: transposes + ELL + W hi/lo fragment split ============
__global__ __launch_bounds__(256) void k_pre(
    const float* __restrict__ c2, const float* __restrict__ c3,
    const float* __restrict__ c4, const float* __restrict__ c5,
    float* __restrict__ t0, float* __restrict__ t1,
    float* __restrict__ t2, float* __restrict__ t3,
    const float* __restrict__ adj, int* __restrict__ cols, int* __restrict__ cnts,
    const float* __restrict__ lin_w,
    unsigned short* __restrict__ whi, unsigned short* __restrict__ wlo) {
  __shared__ float t[32][33];
  int bid = blockIdx.x;
  if (bid < 6144) {
    const float* in; float* out; int C, P, nx, ny, rem;
    if (bid < 3136)      { in = c2; out = t0; C = 256;  P = 3136; nx = 98; ny = 8;  rem = bid; }
    else if (bid < 4736) { in = c3; out = t1; C = 512;  P = 784;  nx = 25; ny = 16; rem = bid - 3136; }
    else if (bid < 5632) { in = c4; out = t2; C = 1024; P = 196;  nx = 7;  ny = 32; rem = bid - 4736; }
    else                 { in = c5; out = t3; C = 2048; P = 49;   nx = 2;  ny = 64; rem = bid - 5632; }
    int x = rem % nx; int tq = rem / nx; int y = tq % ny; int b = tq / ny;
    int p0 = x * 32, c0 = y * 32;
    int lp = threadIdx.x & 31, lc = threadIdx.x >> 5;
    for (int cc = lc; cc < 32; cc += 8) {
      int c = c0 + cc, p = p0 + lp;
      t[cc][lp] = (c < C && p < P) ? in[((size_t)b*C + c)*P + p] : 0.f;
    }
    __syncthreads();
    for (int pp = lc; pp < 32; pp += 8) {
      int p = p0 + pp, c = c0 + lp;
      if (p < P && c < C) out[((size_t)b*P + p)*C + c] = t[lp][pp];
    }
  } else if (bid < 8610) {
    int wave = threadIdx.x >> 6, lane = threadIdx.x & 63;
    int row = (bid - 6144) * 4 + wave;
    const float* Ar = adj + (size_t)row * N_;
    int* cp = cols + (size_t)row * ELLW;
    unsigned long long below = (lane == 63) ? 0xFFFFFFFFFFFFFFFFull >> 1
                                            : ((1ull << lane) - 1ull);
    int base = 0;
    for (int i0 = 0; i0 < 20; i0++) {
      int j0 = i0 * 128 + lane * 2;
      float2 v = make_float2(0.f, 0.f);
      if (j0 + 1 < N_) v = *(const float2*)&Ar[j0];
      bool nz0 = (j0 < N_) && (v.x != 0.f);
      bool nz1 = (j0 + 1 < N_) && (v.y != 0.f);
      unsigned long long m0 = __ballot(nz0);
      unsigned long long m1 = __ballot(nz1);
      int pre = __popcll(m0 & below) + __popcll(m1 & below);
      int p0 = base + pre;
      int p1 = p0 + (nz0 ? 1 : 0);
      if (nz0 && p0 < ELLW) cp[p0] = j0;
      if (nz1 && p1 < ELLW) cp[p1] = j0 + 1;
      base += __popcll(m0) + __popcll(m1);
    }
    if (lane == 0) cnts[row] = (base > ELLW) ? ELLW : base;
  } else {
    // lin_w -> bf16 hi/lo in MFMA B-fragment order:
    // e = ((slab*8 + nt)*64 + lane)*8 + j ; k = slab*32 + (lane>>4)*8 + j ; n = nt*16 + (lane&15)
    int b = bid - 8610;                    // 0..479
    int e0 = (b * 256 + threadIdx.x) * 4;
    #pragma unroll
    for (int u = 0; u < 4; u++) {
      int e = e0 + u;
      int j = e & 7;
      int lane = (e >> 3) & 63;
      int nt = (e >> 9) & 7;
      int slab = e >> 12;
      int k = slab * 32 + ((lane >> 4) << 3) + j;
      int n = nt * 16 + (lane & 15);
      float x = lin_w[(size_t)k * 128 + n];
      unsigned short h = bf16_rne(x);
      whi[e] = h;
      wlo[e] = bf16_rne(x - bf16_back(h));
    }
  }
}

// ============ split-K vertex-align gather + bf16x3 MFMA GEMM ============
// M=128 per block: 4 waves x 2 m-tiles of 16 rows each.
__global__ __launch_bounds__(256) void k_align_mfma(
    const float* __restrict__ tr0, const float* __restrict__ tr1,
    const float* __restrict__ tr2, const float* __restrict__ tr3,
    const float* __restrict__ pos,
    const unsigned short* __restrict__ whi, const unsigned short* __restrict__ wlo,
    float* __restrict__ part, int kchunk) {
  int tid  = threadIdx.x;
  int wave = tid >> 6, lane = tid & 63;
  int q    = lane >> 4, l15 = lane & 15;
  int m0   = blockIdx.x * 128;
  int s    = blockIdx.y;

  float wgt[2][4]; int base[2][4];
  #pragma unroll
  for (int u = 0; u < 2; u++) {
    int mrow = m0 + (wave * 2 + u) * 16 + l15;
    int rowc = (mrow < R_) ? mrow : 0;
    int b = rowc / N_;
    float px = pos[rowc*3+0], py = pos[rowc*3+1], pz = pos[rowc*3+2];
    float hh = fminf(fmaxf(248.f*(py/pz)    + 111.5f, 0.f), 223.f);
    float wc = fminf(fmaxf(248.f*(px/(-pz)) + 111.5f, 0.f), 223.f);
    const int Sarr[4] = {56, 28, 14, 7};
    const int Carr[4] = {256, 512, 1024, 2048};
    #pragma unroll
    for (int sc = 0; sc < 4; sc++) {
      int S = Sarr[sc], C = Carr[sc];
      float dv = 224.f / (float)S;
      float x = hh / dv, y = wc / dv;
      int x1 = (int)floorf(x), y1 = (int)floorf(y);
      int x2 = min((int)ceilf(x), S - 1), y2 = min((int)ceilf(y), S - 1);
      float w = (float)((x2 - x1) * (y2 - y1));   // xi==x1,yi==y1 -> single tap
      if (mrow >= R_) w = 0.f;
      wgt[u][sc]  = w;
      base[u][sc] = (b * S * S + x1 * S + y1) * C;   // NHWC; add channel
    }
  }

  f32x4 acc[2][8];
  #pragma unroll
  for (int u = 0; u < 2; u++)
    #pragma unroll
    for (int nt = 0; nt < 8; nt++) acc[u][nt] = (f32x4){0.f, 0.f, 0.f, 0.f};

  const bf16x8* BH = (const bf16x8*)whi;
  const bf16x8* BL = (const bf16x8*)wlo;

  int kbeg = s * kchunk, kend = kbeg + kchunk;
  #pragma unroll 1
  for (int k0 = kbeg; k0 < kend; k0 += 32) {
    const float* tr; int off, sI;
    if (k0 < 256)       { tr = tr0; off = 0;    sI = 0; }
    else if (k0 < 768)  { tr = tr1; off = 256;  sI = 1; }
    else if (k0 < 1792) { tr = tr2; off = 768;  sI = 2; }
    else                { tr = tr3; off = 1792; sI = 3; }

    bf16x8 ah[2], al[2];
    #pragma unroll
    for (int u = 0; u < 2; u++) {
      const float* src = tr + base[u][sI] + (k0 - off + q * 8);
      float4 a0 = *(const float4*)src;
      float4 a1 = *(const float4*)(src + 4);
      float wg = wgt[u][sI];
      float af[8] = {a0.x*wg, a0.y*wg, a0.z*wg, a0.w*wg,
                     a1.x*wg, a1.y*wg, a1.z*wg, a1.w*wg};
      #pragma unroll
      for (int j = 0; j < 8; j++) {
        unsigned short h = bf16_rne(af[j]);
        ah[u][j] = (short)h;
        al[u][j] = (short)bf16_rne(af[j] - bf16_back(h));
      }
    }

    int slab = k0 >> 5;
    bf16x8 Bh[8], Bl[8];
    #pragma unroll
    for (int nt = 0; nt < 8; nt++) {
      size_t fi = (size_t)(slab * 8 + nt) * 64 + lane;
      Bh[nt] = BH[fi];
      Bl[nt] = BL[fi];
    }
    // hi*hi + lo*hi + hi*lo (lo*lo dropped)
    #pragma unroll
    for (int nt = 0; nt < 8; nt++) {
      acc[0][nt] = __builtin_amdgcn_mfma_f32_16x16x32_bf16(ah[0], Bh[nt], acc[0][nt], 0, 0, 0);
      acc[1][nt] = __builtin_amdgcn_mfma_f32_16x16x32_bf16(ah[1], Bh[nt], acc[1][nt], 0, 0, 0);
    }
    #pragma unroll
    for (int nt = 0; nt < 8; nt++) {
      acc[0][nt] = __builtin_amdgcn_mfma_f32_16x16x32_bf16(al[0], Bh[nt], acc[0][nt], 0, 0, 0);
      acc[1][nt] = __builtin_amdgcn_mfma_f32_16x16x32_bf16(al[1], Bh[nt], acc[1][nt], 0, 0, 0);
    }
    #pragma unroll
    for (int nt = 0; nt < 8; nt++) {
      acc[0][nt] = __builtin_amdgcn_mfma_f32_16x16x32_bf16(ah[0], Bl[nt], acc[0][nt], 0, 0, 0);
      acc[1][nt] = __builtin_amdgcn_mfma_f32_16x16x32_bf16(ah[1], Bl[nt], acc[1][nt], 0, 0, 0);
    }
  }

  // C/D layout: col = lane&15, row_in_tile = q*4 + reg
  #pragma unroll
  for (int u = 0; u < 2; u++)
    #pragma unroll
    for (int nt = 0; nt < 8; nt++)
      #pragma unroll
      for (int r = 0; r < 4; r++) {
        int row = m0 + (wave * 2 + u) * 16 + q * 4 + r;
        if (row < R_)
          part[((size_t)s * R_ + row) * 128 + nt * 16 + l15] = acc[u][nt][r];
      }
}

// ============ fused X-build + GEMM ============
// MODE 0: X = [reduce(part)+lin_b | vf | pos] (K=259); MODE 1: X = relu(s + A@t) (K=128);
// MODE 2: X = skip + relu(s + A@t) (K=128). blockIdx.y = which; NW==3 && which==2 adds pb.
// NOTE: the K-tile loop MUST NOT be unrolled (K is a template constant; full unroll made
// LLVM cluster all W-loads -> 256 VGPR + 1.5 GB/dispatch scratch spill in R7/R8).
template<int MODE, int K, int NW>
__global__ __launch_bounds__(256) void k_fused(
    const float* __restrict__ part, const float* __restrict__ lin_b,
    const float* __restrict__ vf, const float* __restrict__ pos,
    const float* __restrict__ sin_, const float* __restrict__ tin,
    const float* __restrict__ skin,
    const int* __restrict__ cols, const int* __restrict__ cnts,
    const float* __restrict__ W0, const float* __restrict__ W1,
    const float* __restrict__ W2, const float* __restrict__ pb,
    float* __restrict__ o0, float* __restrict__ o1, float* __restrict__ o2,
    int nsplit) {
  constexpr int LDX = (K + 7) & ~3;       // 264 / 132 (16B-aligned row stride)
  __shared__ alignas(16) float X[32][LDX];
  __shared__ alignas(16) float Ws[32][128];
  int tid = threadIdx.x;
  int m0 = blockIdx.x * 32;
  int which = blockIdx.y;
  int grp = tid >> 5, ln = tid & 31;

  if (MODE == 0) {
    #pragma unroll 1
    for (int pass = 0; pass < 4; pass++) {
      int r = pass * 8 + grp;
      int row = m0 + r;
      if (row < R_) {
        float4 a4 = ((const float4*)lin_b)[ln];
        for (int ss = 0; ss < nsplit; ss++) {
          float4 pv = ((const float4*)part)[((size_t)ss * R_ + row) * 32 + ln];
          a4.x += pv.x; a4.y += pv.y; a4.z += pv.z; a4.w += pv.w;
        }
        *(float4*)&X[r][ln * 4] = a4;
        *(float4*)&X[r][128 + ln * 4] = ((const float4*)vf)[(size_t)row * 32 + ln];
        if (ln < 3) X[r][256 + ln] = pos[(size_t)row * 3 + ln];
      } else {
        *(float4*)&X[r][ln * 4] = make_float4(0.f, 0.f, 0.f, 0.f);
        *(float4*)&X[r][128 + ln * 4] = make_float4(0.f, 0.f, 0.f, 0.f);
        if (ln < 3) X[r][256 + ln] = 0.f;
      }
    }
  } else {
    #pragma unroll 1
    for (int pass = 0; pass < 4; pass++) {
      int r = pass * 8 + grp;
      int row = m0 + r;
      float4 acc = make_float4(0.f, 0.f, 0.f, 0.f);
      if (row < R_) {
        int b = row / N_;
        size_t tbase = (size_t)b * N_;
        acc = ((const float4*)sin_)[(size_t)row * 32 + ln];
        int cnt = cnts[row];
        const int* cp = cols + (size_t)row * ELLW;
        for (int i = 0; i < cnt; i++) {
          float4 vv = ((const float4*)tin)[(tbase + cp[i]) * 32 + ln];
          acc.x += vv.x; acc.y += vv.y; acc.z += vv.z; acc.w += vv.w;
        }
        acc.x = fmaxf(acc.x, 0.f); acc.y = fmaxf(acc.y, 0.f);
        acc.z = fmaxf(acc.z, 0.f); acc.w = fmaxf(acc.w, 0.f);
        if (MODE == 2) {
          float4 sk = ((const float4*)skin)[(size_t)row * 32 + ln];
          acc.x += sk.x; acc.y += sk.y; acc.z += sk.z; acc.w += sk.w;
        }
      }
      *(float4*)&X[r][ln * 4] = acc;
    }
  }
  __syncthreads();

  const float* W = (which == 0) ? W0 : (which == 1) ? W1 : W2;
  float* out     = (which == 0) ? o0 : (which == 1) ? o1 : o2;
  int cx = tid & 31, cy = tid >> 5;
  float acc[4][4];
  #pragma unroll
  for (int r = 0; r < 4; r++)
    #pragma unroll
    for (int c = 0; c < 4; c++) acc[r][c] = 0.f;

  constexpr int NTILE = (K + 31) / 32;    // 9 for K=259, 4 for K=128
  constexpr int KR    = K - (K / 32) * 32; // 3 for K=259, 0 for K=128

  #pragma unroll 1
  for (int t = 0; t < NTILE; t++) {
    int k0 = t * 32;
    #pragma unroll
    for (int i = 0; i < 4; i++) {
      int slot = tid + i * 256;
      int kk = slot >> 5, c4 = slot & 31;
      int k = k0 + kk;
      float4 v = make_float4(0.f, 0.f, 0.f, 0.f);
      if (k < K) v = *(const float4*)&W[(size_t)k * 128 + c4 * 4];
      *(float4*)&Ws[kk][c4 * 4] = v;
    }
    __syncthreads();
    if (KR == 0 || t < K / 32) {
      #pragma unroll
      for (int kk = 0; kk < 32; kk++) {
        float av[4];
        #pragma unroll
        for (int r = 0; r < 4; r++) av[r] = X[cy * 4 + r][k0 + kk];
        float4 bv = *(const float4*)&Ws[kk][cx * 4];
        float bb[4] = {bv.x, bv.y, bv.z, bv.w};
        #pragma unroll
        for (int r = 0; r < 4; r++)
          #pragma unroll
          for (int c = 0; c < 4; c++) acc[r][c] += av[r] * bb[c];
      }
    } else {
      #pragma unroll
      for (int kk = 0; kk < (KR ? KR : 1); kk++) {
        float av[4];
        #pragma unroll
        for (int r = 0; r < 4; r++) av[r] = X[cy * 4 + r][k0 + kk];
        float4 bv = *(const float4*)&Ws[kk][cx * 4];
        float bb[4] = {bv.x, bv.y, bv.z, bv.w};
        #pragma unroll
        for (int r = 0; r < 4; r++)
          #pragma unroll
          for (int c = 0; c < 4; c++) acc[r][c] += av[r] * bb[c];
      }
    }
    __syncthreads();
  }

  #pragma unroll
  for (int r = 0; r < 4; r++) {
    int row = m0 + cy * 4 + r;
    if (row < R_) {
      int col = cx * 4;
      float4 v;
      v.x = acc[r][0]; v.y = acc[r][1]; v.z = acc[r][2]; v.w = acc[r][3];
      if (NW == 3 && which == 2) {
        v.x += pb[col + 0]; v.y += pb[col + 1]; v.z += pb[col + 2]; v.w += pb[col + 3];
      }
      *(float4*)&out[(size_t)row * 128 + col] = v;
    }
  }
}

// ---------------- last spmm2 + fused 128->3 GEMV (both gf weights) ----------------
__global__ __launch_bounds__(256) void k_spmm_gf(
    const float* __restrict__ u, const float* __restrict__ v,
    const int* __restrict__ cols, const int* __restrict__ cnts,
    const float* __restrict__ skipb,
    const float* __restrict__ gw0, const float* __restrict__ gw1,
    float* __restrict__ gsb, float* __restrict__ gtb) {
  int tid = threadIdx.x;
  int grp = tid >> 5, ln = tid & 31;
  int row = blockIdx.x * 8 + grp;           // 1233*8 = 9864
  int b = row / N_;
  size_t tbase = (size_t)b * N_;
  float4 acc = ((const float4*)u)[(size_t)row*32 + ln];
  int cnt = cnts[row];
  const int* cp = cols + (size_t)row * ELLW;
  for (int i = 0; i < cnt; i++) {
    float4 vv = ((const float4*)v)[(tbase + cp[i])*32 + ln];
    acc.x += vv.x; acc.y += vv.y; acc.z += vv.z; acc.w += vv.w;
  }
  acc.x = fmaxf(acc.x, 0.f); acc.y = fmaxf(acc.y, 0.f);
  acc.z = fmaxf(acc.z, 0.f); acc.w = fmaxf(acc.w, 0.f);
  float4 sk = ((const float4*)skipb)[(size_t)row*32 + ln];
  acc.x += sk.x; acc.y += sk.y; acc.z += sk.z; acc.w += sk.w;
  float av[4] = {acc.x, acc.y, acc.z, acc.w};
  int j0 = ln * 4;
  float p0 = 0.f, p1 = 0.f, p2 = 0.f, q0 = 0.f, q1 = 0.f, q2 = 0.f;
  #pragma unroll
  for (int uu = 0; uu < 4; uu++) {
    int j = j0 + uu;
    p0 += av[uu] * gw0[j*3+0]; p1 += av[uu] * gw0[j*3+1]; p2 += av[uu] * gw0[j*3+2];
    q0 += av[uu] * gw1[j*3+0]; q1 += av[uu] * gw1[j*3+1]; q2 += av[uu] * gw1[j*3+2];
  }
  #pragma unroll
  for (int off = 16; off >= 1; off >>= 1) {
    p0 += __shfl_xor(p0, off); p1 += __shfl_xor(p1, off); p2 += __shfl_xor(p2, off);
    q0 += __shfl_xor(q0, off); q1 += __shfl_xor(q1, off); q2 += __shfl_xor(q2, off);
  }
  if (ln == 0) {
    gsb[(size_t)row*128 + 0] = p0; gsb[(size_t)row*128 + 1] = p1; gsb[(size_t)row*128 + 2] = p2;
    gtb[(size_t)row*128 + 0] = q0; gtb[(size_t)row*128 + 1] = q1; gtb[(size_t)row*128 + 2] = q2;
  }
}

// ---------------- final: out = pos + tanh(relu(s + A@t)) ----------------
__global__ __launch_bounds__(256) void k_gf_final(
    const float* __restrict__ sb, const float* __restrict__ tb,
    const int* __restrict__ cols, const int* __restrict__ cnts,
    const float* __restrict__ pos, float* __restrict__ out) {
  int wave = threadIdx.x >> 6, lane = threadIdx.x & 63;
  int row = blockIdx.x * 4 + wave;          // grid 2466
  if (lane >= 3) return;
  int b = row / N_;
  float acc = sb[(size_t)row*128 + lane];
  int cnt = cnts[row];
  const int* cp = cols + (size_t)row * ELLW;
  size_t tbase = (size_t)b * N_;
  for (int i = 0; i < cnt; i++)
    acc += tb[(tbase + cp[i])*128 + lane];
  float v = tanhf(fmaxf(acc, 0.f));
  out[(size_t)row*3 + lane] = pos[(size_t)row*3 + lane] + v;
}

extern "C" void kernel_launch(void* const* d_in, const int* in_sizes, int n_in,
                              void* d_out, int out_size, void* d_ws, size_t ws_size,
                              hipStream_t stream) {
  const float* conv2_3 = (const float*)d_in[0];
  const float* conv3_4 = (const float*)d_in[1];
  const float* conv4_6 = (const float*)d_in[2];
  const float* conv5_3 = (const float*)d_in[3];
  const float* pos     = (const float*)d_in[4];
  const float* vf      = (const float*)d_in[5];
  const float* adj     = (const float*)d_in[6];
  const float* lin_w   = (const float*)d_in[7];
  const float* lin_b   = (const float*)d_in[8];
  const float* r_pw[3]  = {(const float*)d_in[9],  (const float*)d_in[15], (const float*)d_in[21]};
  const float* r_pb[3]  = {(const float*)d_in[10], (const float*)d_in[16], (const float*)d_in[22]};
  const float* r_w00[3] = {(const float*)d_in[11], (const float*)d_in[17], (const float*)d_in[23]};
  const float* r_w01[3] = {(const float*)d_in[12], (const float*)d_in[18], (const float*)d_in[24]};
  const float* r_w10[3] = {(const float*)d_in[13], (const float*)d_in[19], (const float*)d_in[25]};
  const float* r_w11[3] = {(const float*)d_in[14], (const float*)d_in[20], (const float*)d_in[26]};
  const float* gf_w0 = (const float*)d_in[27];
  const float* gf_w1 = (const float*)d_in[28];
  float* out = (float*)d_out;

  // ---- workspace layout (float slots) ----
  const size_t TR_TOT = (size_t)4*(256*3136 + 512*784 + 1024*196 + 2048*49); // 6,021,120
  const size_t ELL_I  = (size_t)R_ * (ELLW + 1);                             //   956,808
  const size_t ROWF   = (size_t)R_ * 128;                                    // 1,262,592
  const size_t WS_E   = 491520;                                              // bf16 elems per array

  float* ws  = (float*)d_ws;
  float* tr0 = ws;
  float* tr1 = tr0 + (size_t)4*256*3136;
  float* tr2 = tr1 + (size_t)4*512*784;
  float* tr3 = tr2 + (size_t)4*1024*196;
  int*   ell_cnt  = (int*)(tr3 + (size_t)4*2048*49);
  int*   ell_cols = ell_cnt + R_;
  unsigned short* whi = (unsigned short*)(ell_cols + (size_t)R_*ELLW);
  unsigned short* wlo = whi + WS_E;
  float* part = (float*)(wlo + WS_E);

  size_t fixed_f = TR_TOT + ELL_I + WS_E/2 + WS_E/2;   // tr + ell + whi/wlo (as float slots)
  size_t need8 = (fixed_f + (size_t)13 * ROWF) * sizeof(float);
  int nsplit = (ws_size >= need8) ? 8 : 4;
  int kchunk = 3840 / nsplit;

  float* s_   = part + (size_t)nsplit * ROWF;
  float* t_   = s_   + ROWF;
  float* u_   = t_   + ROWF;
  float* v_   = u_   + ROWF;
  float* skip = v_   + ROWF;
  float* gsb  = part;            // part is dead after the mode-0 k_fused
  float* gtb  = part + ROWF;

  // D0: transposes + ELL + W split
  k_pre<<<9090, 256, 0, stream>>>(conv2_3, conv3_4, conv4_6, conv5_3,
                                  tr0, tr1, tr2, tr3,
                                  adj, ell_cols, ell_cnt,
                                  lin_w, whi, wlo);

  // D1: split-K MFMA align GEMM (M=128 blocks)
  k_align_mfma<<<dim3(78, nsplit), 256, 0, stream>>>(tr0, tr1, tr2, tr3, pos,
                                                     whi, wlo, part, kchunk);

  // D2: reduce+concat -> gemm3 {w00,w01,pw}+pb  => s,t,skip
  k_fused<0,259,3><<<dim3(309,3), 256, 0, stream>>>(
      part, lin_b, vf, pos, nullptr, nullptr, nullptr, nullptr, nullptr,
      r_w00[0], r_w01[0], r_pw[0], r_pb[0], s_, t_, skip, nsplit);

  for (int rb = 0; rb < 3; rb++) {
    // spmm -> gemm2 {w10,w11}  => u,v
    k_fused<1,128,2><<<dim3(309,2), 256, 0, stream>>>(
        nullptr, nullptr, nullptr, nullptr, s_, t_, nullptr, ell_cols, ell_cnt,
        r_w10[rb], r_w11[rb], nullptr, nullptr, u_, v_, nullptr, 0);
    if (rb < 2) {
      // spmm2(+skip) -> gemm3 {w00',w01',pw'}+pb'  => s,t,skip
      k_fused<2,128,3><<<dim3(309,3), 256, 0, stream>>>(
          nullptr, nullptr, nullptr, nullptr, u_, v_, skip, ell_cols, ell_cnt,
          r_w00[rb+1], r_w01[rb+1], r_pw[rb+1], r_pb[rb+1], s_, t_, skip, 0);
    } else {
      // spmm2(+skip) -> fused 128->3 gemv  => gsb,gtb
      k_spmm_gf<<<1233, 256, 0, stream>>>(u_, v_, ell_cols, ell_cnt, skip,
                                          gf_w0, gf_w1, gsb, gtb);
    }
  }

  // D9: out = pos + tanh(relu(gsb + A@gtb))
  k_gf_final<<<2466, 256, 0, stream>>>(gsb, gtb, ell_cols, ell_cnt, pos, out);
}

// Round 10
// 577.672 us; speedup vs baseline: 4.3015x; 1.1271x over previous
//
#include <hip/hip_runtime.h>
#include <cmath>

#define B_   4
#define N_   2466
#define R_   (B_*N_)     // 9864
#define ELLW 96
#define BK   32

typedef __attribute__((ext_vector_type(8))) short bf16x8;
typedef __attribute__((ext_vector_type(4))) float f32x4;

__device__ __forceinline__ unsigned short bf16_rne(float x) {
  union { float f; unsigned u; } c; c.f = x;
  unsigned r = c.u + 0x7FFFu + ((c.u >> 16) & 1u);
  return (unsigned short)(r >> 16);
}
__device__ __forceinline__ float bf16_back(unsigned short h) {
  union { float f; unsigned u; } c; c.u = ((unsigned)h) << 16;
  return c.f;
}

// ============ fused pre-kernel: transposes + ELL + W hi/lo fragment split ============
__global__ __launch_bounds__(256) void k_pre(
    const float* __restrict__ c2, const float* __restrict__ c3,
    const float* __restrict__ c4, const float* __restrict__ c5,
    float* __restrict__ t0, float* __restrict__ t1,
    float* __restrict__ t2, float* __restrict__ t3,
    const float* __restrict__ adj, int* __restrict__ cols, int* __restrict__ cnts,
    const float* __restrict__ lin_w,
    unsigned short* __restrict__ whi, unsigned short* __restrict__ wlo) {
  __shared__ float t[32][33];
  int bid = blockIdx.x;
  if (bid < 6144) {
    const float* in; float* out; int C, P, nx, ny, rem;
    if (bid < 3136)      { in = c2; out = t0; C = 256;  P = 3136; nx = 98; ny = 8;  rem = bid; }
    else if (bid < 4736) { in = c3; out = t1; C = 512;  P = 784;  nx = 25; ny = 16; rem = bid - 3136; }
    else if (bid < 5632) { in = c4; out = t2; C = 1024; P = 196;  nx = 7;  ny = 32; rem = bid - 4736; }
    else                 { in = c5; out = t3; C = 2048; P = 49;   nx = 2;  ny = 64; rem = bid - 5632; }
    int x = rem % nx; int tq = rem / nx; int y = tq % ny; int b = tq / ny;
    int p0 = x * 32, c0 = y * 32;
    int lp = threadIdx.x & 31, lc = threadIdx.x >> 5;
    for (int cc = lc; cc < 32; cc += 8) {
      int c = c0 + cc, p = p0 + lp;
      t[cc][lp] = (c < C && p < P) ? in[((size_t)b*C + c)*P + p] : 0.f;
    }
    __syncthreads();
    for (int pp = lc; pp < 32; pp += 8) {
      int p = p0 + pp, c = c0 + lp;
      if (p < P && c < C) out[((size_t)b*P + p)*C + c] = t[lp][pp];
    }
  } else if (bid < 8610) {
    int wave = threadIdx.x >> 6, lane = threadIdx.x & 63;
    int row = (bid - 6144) * 4 + wave;
    const float* Ar = adj + (size_t)row * N_;
    int* cp = cols + (size_t)row * ELLW;
    unsigned long long below = (lane == 63) ? 0xFFFFFFFFFFFFFFFFull >> 1
                                            : ((1ull << lane) - 1ull);
    int base = 0;
    for (int i0 = 0; i0 < 20; i0++) {
      int j0 = i0 * 128 + lane * 2;
      float2 v = make_float2(0.f, 0.f);
      if (j0 + 1 < N_) v = *(const float2*)&Ar[j0];
      bool nz0 = (j0 < N_) && (v.x != 0.f);
      bool nz1 = (j0 + 1 < N_) && (v.y != 0.f);
      unsigned long long m0 = __ballot(nz0);
      unsigned long long m1 = __ballot(nz1);
      int pre = __popcll(m0 & below) + __popcll(m1 & below);
      int p0 = base + pre;
      int p1 = p0 + (nz0 ? 1 : 0);
      if (nz0 && p0 < ELLW) cp[p0] = j0;
      if (nz1 && p1 < ELLW) cp[p1] = j0 + 1;
      base += __popcll(m0) + __popcll(m1);
    }
    if (lane == 0) cnts[row] = (base > ELLW) ? ELLW : base;
  } else {
    // lin_w -> bf16 hi/lo in MFMA B-fragment order:
    // e = ((slab*8 + nt)*64 + lane)*8 + j ; k = slab*32 + (lane>>4)*8 + j ; n = nt*16 + (lane&15)
    int b = bid - 8610;                    // 0..479
    int e0 = (b * 256 + threadIdx.x) * 4;
    #pragma unroll
    for (int u = 0; u < 4; u++) {
      int e = e0 + u;
      int j = e & 7;
      int lane = (e >> 3) & 63;
      int nt = (e >> 9) & 7;
      int slab = e >> 12;
      int k = slab * 32 + ((lane >> 4) << 3) + j;
      int n = nt * 16 + (lane & 15);
      float x = lin_w[(size_t)k * 128 + n];
      unsigned short h = bf16_rne(x);
      whi[e] = h;
      wlo[e] = bf16_rne(x - bf16_back(h));
    }
  }
}

// ============ split-K vertex-align gather + bf16x3 MFMA GEMM ============
// 512-thread blocks: 8 waves, each wave owns one 16-row m-tile -> M=128/block.
// Same B-reuse as R9's M=128 but 2x the waves/CU (grid-limited occupancy fix).
__global__ __launch_bounds__(512) void k_align_mfma(
    const float* __restrict__ tr0, const float* __restrict__ tr1,
    const float* __restrict__ tr2, const float* __restrict__ tr3,
    const float* __restrict__ pos,
    const unsigned short* __restrict__ whi, const unsigned short* __restrict__ wlo,
    float* __restrict__ part, int kchunk) {
  int tid  = threadIdx.x;
  int wave = tid >> 6, lane = tid & 63;
  int q    = lane >> 4, l15 = lane & 15;
  int m0   = blockIdx.x * 128;
  int s    = blockIdx.y;
  int mrow = m0 + wave * 16 + l15;

  float wgt[4]; int base[4];
  {
    int rowc = (mrow < R_) ? mrow : 0;
    int b = rowc / N_;
    float px = pos[rowc*3+0], py = pos[rowc*3+1], pz = pos[rowc*3+2];
    float hh = fminf(fmaxf(248.f*(py/pz)    + 111.5f, 0.f), 223.f);
    float wc = fminf(fmaxf(248.f*(px/(-pz)) + 111.5f, 0.f), 223.f);
    const int Sarr[4] = {56, 28, 14, 7};
    const int Carr[4] = {256, 512, 1024, 2048};
    #pragma unroll
    for (int sc = 0; sc < 4; sc++) {
      int S = Sarr[sc], C = Carr[sc];
      float dv = 224.f / (float)S;
      float x = hh / dv, y = wc / dv;
      int x1 = (int)floorf(x), y1 = (int)floorf(y);
      int x2 = min((int)ceilf(x), S - 1), y2 = min((int)ceilf(y), S - 1);
      float w = (float)((x2 - x1) * (y2 - y1));   // xi==x1,yi==y1 -> single tap
      if (mrow >= R_) w = 0.f;
      wgt[sc]  = w;
      base[sc] = (b * S * S + x1 * S + y1) * C;   // NHWC; add channel
    }
  }

  f32x4 acc[8];
  #pragma unroll
  for (int nt = 0; nt < 8; nt++) acc[nt] = (f32x4){0.f, 0.f, 0.f, 0.f};

  const bf16x8* BH = (const bf16x8*)whi;
  const bf16x8* BL = (const bf16x8*)wlo;

  int kbeg = s * kchunk, kend = kbeg + kchunk;
  #pragma unroll 1
  for (int k0 = kbeg; k0 < kend; k0 += 32) {
    const float* tr; int off, sI;
    if (k0 < 256)       { tr = tr0; off = 0;    sI = 0; }
    else if (k0 < 768)  { tr = tr1; off = 256;  sI = 1; }
    else if (k0 < 1792) { tr = tr2; off = 768;  sI = 2; }
    else                { tr = tr3; off = 1792; sI = 3; }

    const float* src = tr + base[sI] + (k0 - off + q * 8);
    float4 a0 = *(const float4*)src;
    float4 a1 = *(const float4*)(src + 4);
    float wg = wgt[sI];
    float af[8] = {a0.x*wg, a0.y*wg, a0.z*wg, a0.w*wg,
                   a1.x*wg, a1.y*wg, a1.z*wg, a1.w*wg};
    bf16x8 ahi, alo;
    #pragma unroll
    for (int j = 0; j < 8; j++) {
      unsigned short h = bf16_rne(af[j]);
      ahi[j] = (short)h;
      alo[j] = (short)bf16_rne(af[j] - bf16_back(h));
    }

    int slab = k0 >> 5;
    bf16x8 Bh[8], Bl[8];
    #pragma unroll
    for (int nt = 0; nt < 8; nt++) {
      size_t fi = (size_t)(slab * 8 + nt) * 64 + lane;
      Bh[nt] = BH[fi];
      Bl[nt] = BL[fi];
    }
    // hi*hi + lo*hi + hi*lo (lo*lo dropped)
    #pragma unroll
    for (int nt = 0; nt < 8; nt++)
      acc[nt] = __builtin_amdgcn_mfma_f32_16x16x32_bf16(ahi, Bh[nt], acc[nt], 0, 0, 0);
    #pragma unroll
    for (int nt = 0; nt < 8; nt++)
      acc[nt] = __builtin_amdgcn_mfma_f32_16x16x32_bf16(alo, Bh[nt], acc[nt], 0, 0, 0);
    #pragma unroll
    for (int nt = 0; nt < 8; nt++)
      acc[nt] = __builtin_amdgcn_mfma_f32_16x16x32_bf16(ahi, Bl[nt], acc[nt], 0, 0, 0);
  }

  // C/D layout: col = lane&15, row_in_tile = q*4 + reg
  #pragma unroll
  for (int nt = 0; nt < 8; nt++)
    #pragma unroll
    for (int r = 0; r < 4; r++) {
      int row = m0 + wave * 16 + q * 4 + r;
      if (row < R_)
        part[((size_t)s * R_ + row) * 128 + nt * 16 + l15] = acc[nt][r];
    }
}

// ---------------- reduce partials + bias, build xcat (proj|vf|pos), 2 rows/block ----------------
__global__ __launch_bounds__(256) void k_reduce(
    const float* __restrict__ part, const float* __restrict__ lin_b,
    const float* __restrict__ vf, const float* __restrict__ pos,
    float* __restrict__ xcat, int nsplit) {
  int row = blockIdx.x * 2 + (threadIdx.x >> 7);
  int k = threadIdx.x & 127;
  float acc = lin_b[k];
  for (int s = 0; s < nsplit; s++)
    acc += part[((size_t)s*R_ + row)*128 + k];
  xcat[(size_t)row*264 + k]       = acc;
  xcat[(size_t)row*264 + 128 + k] = vf[(size_t)row*128 + k];
  if (k < 3) xcat[(size_t)row*264 + 256 + k] = pos[(size_t)row*3 + k];
}

// ---------------- tiled GEMM (32x128): out[which] = X @ W[which] (+pb for which==2) ----------------
// Runtime K/ldx on purpose: compile-time K made LLVM fully unroll and spill (R7/R8, 1.5 GB scratch).
__global__ __launch_bounds__(256) void k_gemm(
    const float* __restrict__ X, int ldx, int K,
    const float* __restrict__ W0, const float* __restrict__ W1,
    const float* __restrict__ W2, const float* __restrict__ pb,
    float* __restrict__ o0, float* __restrict__ o1, float* __restrict__ o2) {
  __shared__ alignas(16) float Xs[BK][36];    // pad 36: &Xs[kk][cy*4] is 16B-aligned
  __shared__ alignas(16) float Ws[BK][128];
  int tid = threadIdx.x;
  int m0  = blockIdx.x * 32;
  int which = blockIdx.y;
  const float* W = (which == 0) ? W0 : (which == 1) ? W1 : W2;
  float* out     = (which == 0) ? o0 : (which == 1) ? o1 : o2;

  float acc[4][4];
  #pragma unroll
  for (int r = 0; r < 4; r++)
    #pragma unroll
    for (int c = 0; c < 4; c++) acc[r][c] = 0.f;
  int cx = tid & 31, cy = tid >> 5;

  for (int k0 = 0; k0 < K; k0 += BK) {
    {
      int e = tid;
      #pragma unroll
      for (int i = 0; i < 4; i++) {
        int kk = e & 31, m = e >> 5;
        int row = m0 + m, k = k0 + kk;
        Xs[kk][m] = (row < R_ && k < K) ? X[(size_t)row*ldx + k] : 0.f;
        e += 256;
      }
    }
    #pragma unroll
    for (int i = 0; i < 4; i++) {
      int slot = tid + i * 256;
      int kk = slot >> 5, c4 = slot & 31;
      int k = k0 + kk;
      float4 v = make_float4(0.f, 0.f, 0.f, 0.f);
      if (k < K) v = *(const float4*)&W[(size_t)k*128 + c4*4];
      *(float4*)&Ws[kk][c4*4] = v;
    }
    __syncthreads();
    #pragma unroll
    for (int kk = 0; kk < BK; kk++) {
      float4 av4 = *(const float4*)&Xs[kk][cy*4];
      float4 bv  = *(const float4*)&Ws[kk][cx*4];
      float av[4] = {av4.x, av4.y, av4.z, av4.w};
      float bb[4] = {bv.x, bv.y, bv.z, bv.w};
      #pragma unroll
      for (int r = 0; r < 4; r++)
        #pragma unroll
        for (int c = 0; c < 4; c++) acc[r][c] += av[r] * bb[c];
    }
    __syncthreads();
  }

  #pragma unroll
  for (int r = 0; r < 4; r++) {
    int row = m0 + cy*4 + r;
    if (row < R_) {
      int col = cx * 4;
      float4 v;
      v.x = acc[r][0]; v.y = acc[r][1]; v.z = acc[r][2]; v.w = acc[r][3];
      if (which == 2) { v.x += pb[col+0]; v.y += pb[col+1]; v.z += pb[col+2]; v.w += pb[col+3]; }
      *(float4*)&out[(size_t)row*128 + col] = v;
    }
  }
}

// ---------------- SpMM: out = [skip +] relu(s + A@t); optional fused 128->3 GEMV ----------------
__global__ __launch_bounds__(256) void k_spmm(
    const float* __restrict__ sb, const float* __restrict__ tb,
    const int* __restrict__ cols, const int* __restrict__ cnts,
    const float* __restrict__ skipb, float* __restrict__ outb,
    const float* __restrict__ gw0, const float* __restrict__ gw1,
    float* __restrict__ gsb, float* __restrict__ gtb, int fuse_gf) {
  int tid = threadIdx.x;
  int grp = tid >> 5, ln = tid & 31;
  int row = blockIdx.x * 8 + grp;           // grid 1233 * 8 = 9864 exact
  int b = row / N_;
  size_t tbase = (size_t)b * N_;
  const float4* sb4 = (const float4*)sb;
  const float4* tb4 = (const float4*)tb;
  float4 acc = sb4[(size_t)row*32 + ln];
  int cnt = cnts[row];
  const int* cp = cols + (size_t)row * ELLW;
  for (int i = 0; i < cnt; i++) {
    int c = cp[i];
    float4 v = tb4[(tbase + c)*32 + ln];
    acc.x += v.x; acc.y += v.y; acc.z += v.z; acc.w += v.w;
  }
  acc.x = fmaxf(acc.x, 0.f); acc.y = fmaxf(acc.y, 0.f);
  acc.z = fmaxf(acc.z, 0.f); acc.w = fmaxf(acc.w, 0.f);
  if (skipb) {
    float4 sv = ((const float4*)skipb)[(size_t)row*32 + ln];
    acc.x += sv.x; acc.y += sv.y; acc.z += sv.z; acc.w += sv.w;
  }
  if (!fuse_gf) {
    ((float4*)outb)[(size_t)row*32 + ln] = acc;
    return;
  }
  // fused final gemv: p[c] = sum_j x[j]*gw0[j][c], q likewise
  float av[4] = {acc.x, acc.y, acc.z, acc.w};
  int j0 = ln * 4;
  float p0 = 0.f, p1 = 0.f, p2 = 0.f, q0 = 0.f, q1 = 0.f, q2 = 0.f;
  #pragma unroll
  for (int u = 0; u < 4; u++) {
    int j = j0 + u;
    p0 += av[u] * gw0[j*3+0]; p1 += av[u] * gw0[j*3+1]; p2 += av[u] * gw0[j*3+2];
    q0 += av[u] * gw1[j*3+0]; q1 += av[u] * gw1[j*3+1]; q2 += av[u] * gw1[j*3+2];
  }
  #pragma unroll
  for (int off = 16; off >= 1; off >>= 1) {
    p0 += __shfl_xor(p0, off); p1 += __shfl_xor(p1, off); p2 += __shfl_xor(p2, off);
    q0 += __shfl_xor(q0, off); q1 += __shfl_xor(q1, off); q2 += __shfl_xor(q2, off);
  }
  if (ln == 0) {
    gsb[(size_t)row*128 + 0] = p0; gsb[(size_t)row*128 + 1] = p1; gsb[(size_t)row*128 + 2] = p2;
    gtb[(size_t)row*128 + 0] = q0; gtb[(size_t)row*128 + 1] = q1; gtb[(size_t)row*128 + 2] = q2;
  }
}

// ---------------- final: out = pos + tanh(relu(s + A@t)) ----------------
__global__ __launch_bounds__(256) void k_gf_final(
    const float* __restrict__ sb, const float* __restrict__ tb,
    const int* __restrict__ cols, const int* __restrict__ cnts,
    const float* __restrict__ pos, float* __restrict__ out) {
  int wave = threadIdx.x >> 6, lane = threadIdx.x & 63;
  int row = blockIdx.x * 4 + wave;          // grid 2466
  if (lane >= 3) return;
  int b = row / N_;
  float acc = sb[(size_t)row*128 + lane];
  int cnt = cnts[row];
  const int* cp = cols + (size_t)row * ELLW;
  size_t tbase = (size_t)b * N_;
  for (int i = 0; i < cnt; i++)
    acc += tb[(tbase + cp[i])*128 + lane];
  float v = tanhf(fmaxf(acc, 0.f));
  out[(size_t)row*3 + lane] = pos[(size_t)row*3 + lane] + v;
}

extern "C" void kernel_launch(void* const* d_in, const int* in_sizes, int n_in,
                              void* d_out, int out_size, void* d_ws, size_t ws_size,
                              hipStream_t stream) {
  const float* conv2_3 = (const float*)d_in[0];
  const float* conv3_4 = (const float*)d_in[1];
  const float* conv4_6 = (const float*)d_in[2];
  const float* conv5_3 = (const float*)d_in[3];
  const float* pos     = (const float*)d_in[4];
  const float* vf      = (const float*)d_in[5];
  const float* adj     = (const float*)d_in[6];
  const float* lin_w   = (const float*)d_in[7];
  const float* lin_b   = (const float*)d_in[8];
  const float* r_pw[3]  = {(const float*)d_in[9],  (const float*)d_in[15], (const float*)d_in[21]};
  const float* r_pb[3]  = {(const float*)d_in[10], (const float*)d_in[16], (const float*)d_in[22]};
  const float* r_w00[3] = {(const float*)d_in[11], (const float*)d_in[17], (const float*)d_in[23]};
  const float* r_w01[3] = {(const float*)d_in[12], (const float*)d_in[18], (const float*)d_in[24]};
  const float* r_w10[3] = {(const float*)d_in[13], (const float*)d_in[19], (const float*)d_in[25]};
  const float* r_w11[3] = {(const float*)d_in[14], (const float*)d_in[20], (const float*)d_in[26]};
  const float* gf_w0 = (const float*)d_in[27];
  const float* gf_w1 = (const float*)d_in[28];
  float* out = (float*)d_out;

  // ---- workspace layout (float slots) ----
  const size_t TR_TOT = (size_t)4*(256*3136 + 512*784 + 1024*196 + 2048*49); // 6,021,120
  const size_t ROWF   = (size_t)R_ * 128;                                    // 1,262,592
  const size_t XCAT_F = (size_t)R_ * 264;                                    // 2,604,096
  const size_t WS_E   = 491520;                                              // bf16 elems per array

  float* ws  = (float*)d_ws;
  float* tr0 = ws;
  float* tr1 = tr0 + (size_t)4*256*3136;
  float* tr2 = tr1 + (size_t)4*512*784;
  float* tr3 = tr2 + (size_t)4*1024*196;
  int*   ell_cnt  = (int*)(tr3 + (size_t)4*2048*49);
  int*   ell_cols = ell_cnt + R_;
  unsigned short* whi = (unsigned short*)(ell_cols + (size_t)R_*ELLW);
  unsigned short* wlo = whi + WS_E;
  float* part = (float*)(wlo + WS_E);

  size_t fixed_f = TR_TOT + (size_t)R_*(ELLW+1) + WS_E;   // tr + ell + whi/wlo(as floats)
  size_t need8 = (fixed_f + (size_t)8*ROWF + XCAT_F + 5*ROWF) * sizeof(float);
  int nsplit = (ws_size >= need8) ? 8 : 4;
  int kchunk = 3840 / nsplit;

  float* xcat = part + (size_t)nsplit * ROWF;
  float* sb   = xcat + XCAT_F;
  float* tb   = sb   + ROWF;
  float* skip = tb   + ROWF;
  float* hb   = skip + ROWF;
  float* xc   = hb   + ROWF;

  // D0: transposes + ELL + W split
  k_pre<<<9090, 256, 0, stream>>>(conv2_3, conv3_4, conv4_6, conv5_3,
                                  tr0, tr1, tr2, tr3,
                                  adj, ell_cols, ell_cnt,
                                  lin_w, whi, wlo);

  // D1: split-K MFMA align GEMM (512-thread blocks, M=128)
  k_align_mfma<<<dim3(78, nsplit), 512, 0, stream>>>(tr0, tr1, tr2, tr3, pos,
                                                     whi, wlo, part, kchunk);

  // D2: reduce partials + concat
  k_reduce<<<4932, 256, 0, stream>>>(part, lin_b, vf, pos, xcat, nsplit);

  // D3..: three residual graph-conv blocks (R5-proven separate kernels)
  const float* xin = xcat; int ldx = 264, K = 259;
  for (int rb = 0; rb < 3; rb++) {
    k_gemm<<<dim3(309, 3), 256, 0, stream>>>(xin, ldx, K,
        r_w00[rb], r_w01[rb], r_pw[rb], r_pb[rb], sb, tb, skip);
    k_spmm<<<1233, 256, 0, stream>>>(sb, tb, ell_cols, ell_cnt, nullptr, hb,
                                     nullptr, nullptr, nullptr, nullptr, 0);
    k_gemm<<<dim3(309, 2), 256, 0, stream>>>(hb, 128, 128,
        r_w10[rb], r_w11[rb], nullptr, nullptr, sb, tb, nullptr);
    if (rb < 2) {
      k_spmm<<<1233, 256, 0, stream>>>(sb, tb, ell_cols, ell_cnt, skip, xc,
                                       nullptr, nullptr, nullptr, nullptr, 0);
    } else {
      k_spmm<<<1233, 256, 0, stream>>>(sb, tb, ell_cols, ell_cnt, skip, nullptr,
                                       gf_w0, gf_w1, hb, xc, 1);   // gsb=hb, gtb=xc
    }
    xin = xc; ldx = 128; K = 128;
  }

  // final: out = pos + tanh(relu(gsb + A@gtb))
  k_gf_final<<<2466, 256, 0, stream>>>(hb, xc, ell_cols, ell_cnt, pos, out);
}

// Round 11
// 539.733 us; speedup vs baseline: 4.6038x; 1.0703x over previous
//
#include <hip/hip_runtime.h>
#include <cmath>

#define B_   4
#define N_   2466
#define R_   (B_*N_)     // 9864
#define ELLW 96

typedef __attribute__((ext_vector_type(8))) short bf16x8;
typedef __attribute__((ext_vector_type(4))) float f32x4;

__device__ __forceinline__ unsigned short bf16_rne(float x) {
  union { float f; unsigned u; } c; c.f = x;
  unsigned r = c.u + 0x7FFFu + ((c.u >> 16) & 1u);
  return (unsigned short)(r >> 16);
}
__device__ __forceinline__ float bf16_back(unsigned short h) {
  union { float f; unsigned u; } c; c.u = ((unsigned)h) << 16;
  return c.f;
}

struct WMats { const float* p[15]; };   // rb-major: w00,w01,pw,w10,w11

// Fragment-order destination layout (both lin_w and res weights):
// e = ((slab*8 + nt)*64 + lane)*8 + j ; k = slab*32 + (lane>>4)*8 + j ; n = nt*16 + (lane&15)
// Res-weight frag segments (shorts): rb0 {3x36864 (K=259), 2x16384 (K=128)} = 143360;
// rb1/rb2 {5x16384} = 81920 each. Total 307200.

// ============ fused pre-kernel: transposes + ELL + all W hi/lo fragment splits ============
__global__ __launch_bounds__(256) void k_pre(
    const float* __restrict__ c2, const float* __restrict__ c3,
    const float* __restrict__ c4, const float* __restrict__ c5,
    float* __restrict__ t0, float* __restrict__ t1,
    float* __restrict__ t2, float* __restrict__ t3,
    const float* __restrict__ adj, int* __restrict__ cols, int* __restrict__ cnts,
    const float* __restrict__ lin_w,
    unsigned short* __restrict__ whi, unsigned short* __restrict__ wlo,
    WMats wm,
    unsigned short* __restrict__ wrh, unsigned short* __restrict__ wrl) {
  __shared__ float t[32][33];
  int bid = blockIdx.x;
  if (bid < 6144) {
    const float* in; float* out; int C, P, nx, ny, rem;
    if (bid < 3136)      { in = c2; out = t0; C = 256;  P = 3136; nx = 98; ny = 8;  rem = bid; }
    else if (bid < 4736) { in = c3; out = t1; C = 512;  P = 784;  nx = 25; ny = 16; rem = bid - 3136; }
    else if (bid < 5632) { in = c4; out = t2; C = 1024; P = 196;  nx = 7;  ny = 32; rem = bid - 4736; }
    else                 { in = c5; out = t3; C = 2048; P = 49;   nx = 2;  ny = 64; rem = bid - 5632; }
    int x = rem % nx; int tq = rem / nx; int y = tq % ny; int b = tq / ny;
    int p0 = x * 32, c0 = y * 32;
    int lp = threadIdx.x & 31, lc = threadIdx.x >> 5;
    for (int cc = lc; cc < 32; cc += 8) {
      int c = c0 + cc, p = p0 + lp;
      t[cc][lp] = (c < C && p < P) ? in[((size_t)b*C + c)*P + p] : 0.f;
    }
    __syncthreads();
    for (int pp = lc; pp < 32; pp += 8) {
      int p = p0 + pp, c = c0 + lp;
      if (p < P && c < C) out[((size_t)b*P + p)*C + c] = t[lp][pp];
    }
  } else if (bid < 8610) {
    int wave = threadIdx.x >> 6, lane = threadIdx.x & 63;
    int row = (bid - 6144) * 4 + wave;
    const float* Ar = adj + (size_t)row * N_;
    int* cp = cols + (size_t)row * ELLW;
    unsigned long long below = (lane == 63) ? 0xFFFFFFFFFFFFFFFFull >> 1
                                            : ((1ull << lane) - 1ull);
    int base = 0;
    for (int i0 = 0; i0 < 20; i0++) {
      int j0 = i0 * 128 + lane * 2;
      float2 v = make_float2(0.f, 0.f);
      if (j0 + 1 < N_) v = *(const float2*)&Ar[j0];
      bool nz0 = (j0 < N_) && (v.x != 0.f);
      bool nz1 = (j0 + 1 < N_) && (v.y != 0.f);
      unsigned long long m0 = __ballot(nz0);
      unsigned long long m1 = __ballot(nz1);
      int pre = __popcll(m0 & below) + __popcll(m1 & below);
      int p0 = base + pre;
      int p1 = p0 + (nz0 ? 1 : 0);
      if (nz0 && p0 < ELLW) cp[p0] = j0;
      if (nz1 && p1 < ELLW) cp[p1] = j0 + 1;
      base += __popcll(m0) + __popcll(m1);
    }
    if (lane == 0) cnts[row] = (base > ELLW) ? ELLW : base;
  } else if (bid < 9090) {
    // lin_w -> bf16 hi/lo fragments (491520 elems)
    int b = bid - 8610;
    int e0 = (b * 256 + threadIdx.x) * 4;
    #pragma unroll
    for (int u = 0; u < 4; u++) {
      int e = e0 + u;
      int j = e & 7;
      int lane = (e >> 3) & 63;
      int nt = (e >> 9) & 7;
      int slab = e >> 12;
      int k = slab * 32 + ((lane >> 4) << 3) + j;
      int n = nt * 16 + (lane & 15);
      float x = lin_w[(size_t)k * 128 + n];
      unsigned short h = bf16_rne(x);
      whi[e] = h;
      wlo[e] = bf16_rne(x - bf16_back(h));
    }
  } else {
    // res weights -> bf16 hi/lo fragments (307200 elems, zero-padded past K)
    int b = bid - 9090;                 // 0..299
    int e0 = (b * 256 + threadIdx.x) * 4;
    #pragma unroll
    for (int u = 0; u < 4; u++) {
      int e = e0 + u;                   // < 307200 (dest index == e)
      int rb, mat, rem, K;
      if (e < 143360) {
        rb = 0;
        if (e < 110592) { mat = e / 36864; rem = e - mat * 36864; K = 259; }
        else { int tt = e - 110592; mat = 3 + tt / 16384; rem = tt & 16383; K = 128; }
      } else {
        int tt = e - 143360;
        rb = 1 + tt / 81920;
        int r2 = tt % 81920;
        mat = r2 / 16384; rem = r2 & 16383; K = 128;
      }
      int j = rem & 7, lane = (rem >> 3) & 63, nt = (rem >> 9) & 7, slab = rem >> 12;
      int k = slab * 32 + ((lane >> 4) << 3) + j;
      int n = nt * 16 + (lane & 15);
      float x = (k < K) ? wm.p[rb * 5 + mat][(size_t)k * 128 + n] : 0.f;
      unsigned short h = bf16_rne(x);
      wrh[e] = h;
      wrl[e] = bf16_rne(x - bf16_back(h));
    }
  }
}

// ============ split-K vertex-align gather + bf16x3 MFMA GEMM, A-prefetch pipelined ============
__global__ __launch_bounds__(512) void k_align_mfma(
    const float* __restrict__ tr0, const float* __restrict__ tr1,
    const float* __restrict__ tr2, const float* __restrict__ tr3,
    const float* __restrict__ pos,
    const unsigned short* __restrict__ whi, const unsigned short* __restrict__ wlo,
    float* __restrict__ part, int kchunk) {
  int tid  = threadIdx.x;
  int wave = tid >> 6, lane = tid & 63;
  int q    = lane >> 4, l15 = lane & 15;
  int m0   = blockIdx.x * 128;
  int s    = blockIdx.y;
  int mrow = m0 + wave * 16 + l15;

  float wgt[4]; int base[4];
  {
    int rowc = (mrow < R_) ? mrow : 0;
    int b = rowc / N_;
    float px = pos[rowc*3+0], py = pos[rowc*3+1], pz = pos[rowc*3+2];
    float hh = fminf(fmaxf(248.f*(py/pz)    + 111.5f, 0.f), 223.f);
    float wc = fminf(fmaxf(248.f*(px/(-pz)) + 111.5f, 0.f), 223.f);
    const int Sarr[4] = {56, 28, 14, 7};
    const int Carr[4] = {256, 512, 1024, 2048};
    #pragma unroll
    for (int sc = 0; sc < 4; sc++) {
      int S = Sarr[sc], C = Carr[sc];
      float dv = 224.f / (float)S;
      float x = hh / dv, y = wc / dv;
      int x1 = (int)floorf(x), y1 = (int)floorf(y);
      int x2 = min((int)ceilf(x), S - 1), y2 = min((int)ceilf(y), S - 1);
      float w = (float)((x2 - x1) * (y2 - y1));   // xi==x1,yi==y1 -> single tap
      if (mrow >= R_) w = 0.f;
      wgt[sc]  = w;
      base[sc] = (b * S * S + x1 * S + y1) * C;   // NHWC; add channel
    }
  }

  f32x4 acc[8];
  #pragma unroll
  for (int nt = 0; nt < 8; nt++) acc[nt] = (f32x4){0.f, 0.f, 0.f, 0.f};

  const bf16x8* BH = (const bf16x8*)whi;
  const bf16x8* BL = (const bf16x8*)wlo;

  int kbeg = s * kchunk, kend = kbeg + kchunk;
  // A-prefetch prologue
  float4 a0, a1; float wgc;
  {
    const float* tr; int off, sI;
    if (kbeg < 256)       { tr = tr0; off = 0;    sI = 0; }
    else if (kbeg < 768)  { tr = tr1; off = 256;  sI = 1; }
    else if (kbeg < 1792) { tr = tr2; off = 768;  sI = 2; }
    else                  { tr = tr3; off = 1792; sI = 3; }
    const float* src = tr + base[sI] + (kbeg - off + q * 8);
    a0 = *(const float4*)src;
    a1 = *(const float4*)(src + 4);
    wgc = wgt[sI];
  }

  #pragma unroll 1
  for (int k0 = kbeg; k0 < kend; k0 += 32) {
    int slab = k0 >> 5;
    // prefetch next iteration's A (hides scattered-gather latency behind MFMAs)
    float4 na0 = make_float4(0.f,0.f,0.f,0.f), na1 = na0;
    float wgn = 0.f;
    int kn = k0 + 32;
    if (kn < kend) {
      const float* tr; int off, sI;
      if (kn < 256)       { tr = tr0; off = 0;    sI = 0; }
      else if (kn < 768)  { tr = tr1; off = 256;  sI = 1; }
      else if (kn < 1792) { tr = tr2; off = 768;  sI = 2; }
      else                { tr = tr3; off = 1792; sI = 3; }
      const float* nsrc = tr + base[sI] + (kn - off + q * 8);
      na0 = *(const float4*)nsrc;
      na1 = *(const float4*)(nsrc + 4);
      wgn = wgt[sI];
    }

    float af[8] = {a0.x*wgc, a0.y*wgc, a0.z*wgc, a0.w*wgc,
                   a1.x*wgc, a1.y*wgc, a1.z*wgc, a1.w*wgc};
    bf16x8 ahi, alo;
    #pragma unroll
    for (int j = 0; j < 8; j++) {
      unsigned short h = bf16_rne(af[j]);
      ahi[j] = (short)h;
      alo[j] = (short)bf16_rne(af[j] - bf16_back(h));
    }

    bf16x8 Bh[8], Bl[8];
    #pragma unroll
    for (int nt = 0; nt < 8; nt++) {
      size_t fi = (size_t)(slab * 8 + nt) * 64 + lane;
      Bh[nt] = BH[fi];
      Bl[nt] = BL[fi];
    }
    // hi*hi + lo*hi + hi*lo (lo*lo dropped)
    #pragma unroll
    for (int nt = 0; nt < 8; nt++)
      acc[nt] = __builtin_amdgcn_mfma_f32_16x16x32_bf16(ahi, Bh[nt], acc[nt], 0, 0, 0);
    #pragma unroll
    for (int nt = 0; nt < 8; nt++)
      acc[nt] = __builtin_amdgcn_mfma_f32_16x16x32_bf16(alo, Bh[nt], acc[nt], 0, 0, 0);
    #pragma unroll
    for (int nt = 0; nt < 8; nt++)
      acc[nt] = __builtin_amdgcn_mfma_f32_16x16x32_bf16(ahi, Bl[nt], acc[nt], 0, 0, 0);

    a0 = na0; a1 = na1; wgc = wgn;
  }

  // C/D layout: col = lane&15, row_in_tile = q*4 + reg
  #pragma unroll
  for (int nt = 0; nt < 8; nt++)
    #pragma unroll
    for (int r = 0; r < 4; r++) {
      int row = m0 + wave * 16 + q * 4 + r;
      if (row < R_)
        part[((size_t)s * R_ + row) * 128 + nt * 16 + l15] = acc[nt][r];
    }
}

// ---------------- reduce partials + bias, build xcat (proj|vf|pos|0pad), stride 288 ----------------
__global__ __launch_bounds__(256) void k_reduce(
    const float* __restrict__ part, const float* __restrict__ lin_b,
    const float* __restrict__ vf, const float* __restrict__ pos,
    float* __restrict__ xcat, int nsplit) {
  int row = blockIdx.x * 2 + (threadIdx.x >> 7);
  int k = threadIdx.x & 127;
  float acc = lin_b[k];
  for (int s = 0; s < nsplit; s++)
    acc += part[((size_t)s*R_ + row)*128 + k];
  xcat[(size_t)row*288 + k]       = acc;
  xcat[(size_t)row*288 + 128 + k] = vf[(size_t)row*128 + k];
  if (k < 32) xcat[(size_t)row*288 + 256 + k] = (k < 3) ? pos[(size_t)row*3 + k] : 0.f;
}

// ============ bf16x3 MFMA GEMM: out[which] = X @ W[which] (+pb for which==2) ============
// M=64/block (4 waves x 16-row m-tiles), N=128, W pre-split in fragment order.
template<int SLABS>
__global__ __launch_bounds__(256) void k_gemm_mfma(
    const float* __restrict__ X, int ldx,
    const unsigned short* __restrict__ wh, const unsigned short* __restrict__ wl,
    int matStride, const float* __restrict__ pb,
    float* __restrict__ o0, float* __restrict__ o1, float* __restrict__ o2) {
  int tid = threadIdx.x;
  int wave = tid >> 6, lane = tid & 63;
  int q = lane >> 4, l15 = lane & 15;
  int which = blockIdx.y;
  int m0 = blockIdx.x * 64;
  int mrow = m0 + wave * 16 + l15;
  int rowc = (mrow < R_) ? mrow : (R_ - 1);
  const float* xrow = X + (size_t)rowc * ldx + q * 8;

  const bf16x8* BH = (const bf16x8*)(wh + (size_t)which * matStride);
  const bf16x8* BL = (const bf16x8*)(wl + (size_t)which * matStride);

  f32x4 acc[8];
  #pragma unroll
  for (int nt = 0; nt < 8; nt++) acc[nt] = (f32x4){0.f, 0.f, 0.f, 0.f};

  #pragma unroll 1
  for (int slab = 0; slab < SLABS; slab++) {
    const float* src = xrow + slab * 32;
    float4 a0 = *(const float4*)src;
    float4 a1 = *(const float4*)(src + 4);
    float af[8] = {a0.x, a0.y, a0.z, a0.w, a1.x, a1.y, a1.z, a1.w};
    bf16x8 ahi, alo;
    #pragma unroll
    for (int j = 0; j < 8; j++) {
      unsigned short h = bf16_rne(af[j]);
      ahi[j] = (short)h;
      alo[j] = (short)bf16_rne(af[j] - bf16_back(h));
    }
    bf16x8 Bh[8], Bl[8];
    #pragma unroll
    for (int nt = 0; nt < 8; nt++) {
      size_t fi = (size_t)(slab * 8 + nt) * 64 + lane;
      Bh[nt] = BH[fi];
      Bl[nt] = BL[fi];
    }
    #pragma unroll
    for (int nt = 0; nt < 8; nt++)
      acc[nt] = __builtin_amdgcn_mfma_f32_16x16x32_bf16(ahi, Bh[nt], acc[nt], 0, 0, 0);
    #pragma unroll
    for (int nt = 0; nt < 8; nt++)
      acc[nt] = __builtin_amdgcn_mfma_f32_16x16x32_bf16(alo, Bh[nt], acc[nt], 0, 0, 0);
    #pragma unroll
    for (int nt = 0; nt < 8; nt++)
      acc[nt] = __builtin_amdgcn_mfma_f32_16x16x32_bf16(ahi, Bl[nt], acc[nt], 0, 0, 0);
  }

  float* out = (which == 0) ? o0 : (which == 1) ? o1 : o2;
  #pragma unroll
  for (int nt = 0; nt < 8; nt++) {
    int col = nt * 16 + l15;
    float bias = (pb != nullptr && which == 2) ? pb[col] : 0.f;
    #pragma unroll
    for (int r = 0; r < 4; r++) {
      int row = m0 + wave * 16 + q * 4 + r;
      if (row < R_) out[(size_t)row * 128 + col] = acc[nt][r] + bias;
    }
  }
}

// ---------------- SpMM: out = [skip +] relu(s + A@t); optional fused 128->3 GEMV ----------------
__global__ __launch_bounds__(256) void k_spmm(
    const float* __restrict__ sb, const float* __restrict__ tb,
    const int* __restrict__ cols, const int* __restrict__ cnts,
    const float* __restrict__ skipb, float* __restrict__ outb,
    const float* __restrict__ gw0, const float* __restrict__ gw1,
    float* __restrict__ gsb, float* __restrict__ gtb, int fuse_gf) {
  int tid = threadIdx.x;
  int grp = tid >> 5, ln = tid & 31;
  int row = blockIdx.x * 8 + grp;           // 1233 * 8 = 9864 exact
  int b = row / N_;
  size_t tbase = (size_t)b * N_;
  const float4* sb4 = (const float4*)sb;
  const float4* tb4 = (const float4*)tb;
  float4 acc = sb4[(size_t)row*32 + ln];
  int cnt = cnts[row];
  const int* cp = cols + (size_t)row * ELLW;
  for (int i = 0; i < cnt; i++) {
    int c = cp[i];
    float4 v = tb4[(tbase + c)*32 + ln];
    acc.x += v.x; acc.y += v.y; acc.z += v.z; acc.w += v.w;
  }
  acc.x = fmaxf(acc.x, 0.f); acc.y = fmaxf(acc.y, 0.f);
  acc.z = fmaxf(acc.z, 0.f); acc.w = fmaxf(acc.w, 0.f);
  if (skipb) {
    float4 sv = ((const float4*)skipb)[(size_t)row*32 + ln];
    acc.x += sv.x; acc.y += sv.y; acc.z += sv.z; acc.w += sv.w;
  }
  if (!fuse_gf) {
    ((float4*)outb)[(size_t)row*32 + ln] = acc;
    return;
  }
  float av[4] = {acc.x, acc.y, acc.z, acc.w};
  int j0 = ln * 4;
  float p0 = 0.f, p1 = 0.f, p2 = 0.f, q0 = 0.f, q1 = 0.f, q2 = 0.f;
  #pragma unroll
  for (int u = 0; u < 4; u++) {
    int j = j0 + u;
    p0 += av[u] * gw0[j*3+0]; p1 += av[u] * gw0[j*3+1]; p2 += av[u] * gw0[j*3+2];
    q0 += av[u] * gw1[j*3+0]; q1 += av[u] * gw1[j*3+1]; q2 += av[u] * gw1[j*3+2];
  }
  #pragma unroll
  for (int off = 16; off >= 1; off >>= 1) {
    p0 += __shfl_xor(p0, off); p1 += __shfl_xor(p1, off); p2 += __shfl_xor(p2, off);
    q0 += __shfl_xor(q0, off); q1 += __shfl_xor(q1, off); q2 += __shfl_xor(q2, off);
  }
  if (ln == 0) {
    gsb[(size_t)row*128 + 0] = p0; gsb[(size_t)row*128 + 1] = p1; gsb[(size_t)row*128 + 2] = p2;
    gtb[(size_t)row*128 + 0] = q0; gtb[(size_t)row*128 + 1] = q1; gtb[(size_t)row*128 + 2] = q2;
  }
}

// ---------------- final: out = pos + tanh(relu(s + A@t)) ----------------
__global__ __launch_bounds__(256) void k_gf_final(
    const float* __restrict__ sb, const float* __restrict__ tb,
    const int* __restrict__ cols, const int* __restrict__ cnts,
    const float* __restrict__ pos, float* __restrict__ out) {
  int wave = threadIdx.x >> 6, lane = threadIdx.x & 63;
  int row = blockIdx.x * 4 + wave;          // grid 2466
  if (lane >= 3) return;
  int b = row / N_;
  float acc = sb[(size_t)row*128 + lane];
  int cnt = cnts[row];
  const int* cp = cols + (size_t)row * ELLW;
  size_t tbase = (size_t)b * N_;
  for (int i = 0; i < cnt; i++)
    acc += tb[(tbase + cp[i])*128 + lane];
  float v = tanhf(fmaxf(acc, 0.f));
  out[(size_t)row*3 + lane] = pos[(size_t)row*3 + lane] + v;
}

extern "C" void kernel_launch(void* const* d_in, const int* in_sizes, int n_in,
                              void* d_out, int out_size, void* d_ws, size_t ws_size,
                              hipStream_t stream) {
  const float* conv2_3 = (const float*)d_in[0];
  const float* conv3_4 = (const float*)d_in[1];
  const float* conv4_6 = (const float*)d_in[2];
  const float* conv5_3 = (const float*)d_in[3];
  const float* pos     = (const float*)d_in[4];
  const float* vf      = (const float*)d_in[5];
  const float* adj     = (const float*)d_in[6];
  const float* lin_w   = (const float*)d_in[7];
  const float* lin_b   = (const float*)d_in[8];
  const float* r_pb[3]  = {(const float*)d_in[10], (const float*)d_in[16], (const float*)d_in[22]};
  const float* gf_w0 = (const float*)d_in[27];
  const float* gf_w1 = (const float*)d_in[28];
  float* out = (float*)d_out;

  // ---- workspace layout (float slots) ----
  const size_t TR_TOT  = (size_t)4*(256*3136 + 512*784 + 1024*196 + 2048*49); // 6,021,120
  const size_t ROWF    = (size_t)R_ * 128;                                    // 1,262,592
  const size_t XCAT_F  = (size_t)R_ * 288;                                    // 2,840,832
  const size_t LINW_E  = 491520;                                              // shorts per array
  const size_t RESW_E  = 307200;                                              // shorts per array

  float* ws  = (float*)d_ws;
  float* tr0 = ws;
  float* tr1 = tr0 + (size_t)4*256*3136;
  float* tr2 = tr1 + (size_t)4*512*784;
  float* tr3 = tr2 + (size_t)4*1024*196;
  int*   ell_cnt  = (int*)(tr3 + (size_t)4*2048*49);
  int*   ell_cols = ell_cnt + R_;
  unsigned short* whi = (unsigned short*)(ell_cols + (size_t)R_*ELLW);
  unsigned short* wlo = whi + LINW_E;
  unsigned short* wrh = wlo + LINW_E;
  unsigned short* wrl = wrh + RESW_E;
  float* part = (float*)(wrl + RESW_E);    // byte offset is 16B-aligned (all segs /16)

  size_t fixed_f = TR_TOT + (size_t)R_*(ELLW+1) + LINW_E + RESW_E;  // shorts pairs = float slots
  size_t need8 = (fixed_f + (size_t)8*ROWF + XCAT_F + 5*ROWF) * sizeof(float);
  int nsplit = (ws_size >= need8) ? 8 : 4;
  int kchunk = 3840 / nsplit;

  float* xcat = part + (size_t)nsplit * ROWF;
  float* sb   = xcat + XCAT_F;
  float* tb   = sb   + ROWF;
  float* skip = tb   + ROWF;
  float* hb   = skip + ROWF;
  float* xc   = hb   + ROWF;

  WMats wm;
  for (int rb = 0; rb < 3; rb++) {
    wm.p[rb*5 + 0] = (const float*)d_in[11 + 6*rb];  // w00
    wm.p[rb*5 + 1] = (const float*)d_in[12 + 6*rb];  // w01
    wm.p[rb*5 + 2] = (const float*)d_in[9  + 6*rb];  // pw
    wm.p[rb*5 + 3] = (const float*)d_in[13 + 6*rb];  // w10
    wm.p[rb*5 + 4] = (const float*)d_in[14 + 6*rb];  // w11
  }
  // frag-segment bases (shorts): rb0 @0 (gemm3 stride 36864, gemm2 @110592 stride 16384);
  // rb1 @143360, rb2 @225280 (all strides 16384; gemm2 offset +3*16384)
  const int RB_BASE[3] = {0, 143360, 225280};

  // D0: transposes + ELL + all W splits
  k_pre<<<9390, 256, 0, stream>>>(conv2_3, conv3_4, conv4_6, conv5_3,
                                  tr0, tr1, tr2, tr3,
                                  adj, ell_cols, ell_cnt,
                                  lin_w, whi, wlo, wm, wrh, wrl);

  // D1: split-K MFMA align GEMM (512-thread blocks, M=128, A-prefetch)
  k_align_mfma<<<dim3(78, nsplit), 512, 0, stream>>>(tr0, tr1, tr2, tr3, pos,
                                                     whi, wlo, part, kchunk);

  // D2: reduce partials + concat (stride 288, zero-padded)
  k_reduce<<<4932, 256, 0, stream>>>(part, lin_b, vf, pos, xcat, nsplit);

  // D3..: three residual graph-conv blocks, all GEMMs via bf16x3 MFMA
  for (int rb = 0; rb < 3; rb++) {
    if (rb == 0) {
      k_gemm_mfma<9><<<dim3(155, 3), 256, 0, stream>>>(
          xcat, 288, wrh + RB_BASE[0], wrl + RB_BASE[0], 36864, r_pb[0], sb, tb, skip);
    } else {
      k_gemm_mfma<4><<<dim3(155, 3), 256, 0, stream>>>(
          xc, 128, wrh + RB_BASE[rb], wrl + RB_BASE[rb], 16384, r_pb[rb], sb, tb, skip);
    }
    k_spmm<<<1233, 256, 0, stream>>>(sb, tb, ell_cols, ell_cnt, nullptr, hb,
                                     nullptr, nullptr, nullptr, nullptr, 0);
    int g2off = RB_BASE[rb] + ((rb == 0) ? 110592 : 3 * 16384);
    k_gemm_mfma<4><<<dim3(155, 2), 256, 0, stream>>>(
        hb, 128, wrh + g2off, wrl + g2off, 16384, nullptr, sb, tb, nullptr);
    if (rb < 2) {
      k_spmm<<<1233, 256, 0, stream>>>(sb, tb, ell_cols, ell_cnt, skip, xc,
                                       nullptr, nullptr, nullptr, nullptr, 0);
    } else {
      k_spmm<<<1233, 256, 0, stream>>>(sb, tb, ell_cols, ell_cnt, skip, nullptr,
                                       gf_w0, gf_w1, hb, xc, 1);   // gsb=hb, gtb=xc
    }
  }

  // final: out = pos + tanh(relu(gsb + A@gtb))
  k_gf_final<<<2466, 256, 0, stream>>>(hb, xc, ell_cols, ell_cnt, pos, out);
}

// Round 12
// 519.904 us; speedup vs baseline: 4.7794x; 1.0381x over previous
//
#include <hip/hip_runtime.h>
#include <cmath>

#define B_   4
#define N_   2466
#define R_   (B_*N_)     // 9864
#define ELLW 96

typedef __attribute__((ext_vector_type(8))) short bf16x8;
typedef __attribute__((ext_vector_type(4))) float f32x4;

__device__ __forceinline__ unsigned short bf16_rne(float x) {
  union { float f; unsigned u; } c; c.f = x;
  unsigned r = c.u + 0x7FFFu + ((c.u >> 16) & 1u);
  return (unsigned short)(r >> 16);
}
__device__ __forceinline__ float bf16_back(unsigned short h) {
  union { float f; unsigned u; } c; c.u = ((unsigned)h) << 16;
  return c.f;
}

struct WMats { const float* p[15]; };   // rb-major: w00,w01,pw,w10,w11

// Fragment-order layout (lin_w and res weights):
// e = ((slab*8 + nt)*64 + lane)*8 + j ; k = slab*32 + (lane>>4)*8 + j ; n = nt*16 + (lane&15)

// ============ fused pre-kernel: transposes + ELL + all W hi/lo fragment splits ============
__global__ __launch_bounds__(256) void k_pre(
    const float* __restrict__ c2, const float* __restrict__ c3,
    const float* __restrict__ c4, const float* __restrict__ c5,
    float* __restrict__ t0, float* __restrict__ t1,
    float* __restrict__ t2, float* __restrict__ t3,
    const float* __restrict__ adj, int* __restrict__ cols, int* __restrict__ cnts,
    const float* __restrict__ lin_w,
    unsigned short* __restrict__ whi, unsigned short* __restrict__ wlo,
    WMats wm,
    unsigned short* __restrict__ wrh, unsigned short* __restrict__ wrl) {
  __shared__ float t[32][33];
  int bid = blockIdx.x;
  if (bid < 6144) {
    const float* in; float* out; int C, P, nx, ny, rem;
    if (bid < 3136)      { in = c2; out = t0; C = 256;  P = 3136; nx = 98; ny = 8;  rem = bid; }
    else if (bid < 4736) { in = c3; out = t1; C = 512;  P = 784;  nx = 25; ny = 16; rem = bid - 3136; }
    else if (bid < 5632) { in = c4; out = t2; C = 1024; P = 196;  nx = 7;  ny = 32; rem = bid - 4736; }
    else                 { in = c5; out = t3; C = 2048; P = 49;   nx = 2;  ny = 64; rem = bid - 5632; }
    int x = rem % nx; int tq = rem / nx; int y = tq % ny; int b = tq / ny;
    int p0 = x * 32, c0 = y * 32;
    int lp = threadIdx.x & 31, lc = threadIdx.x >> 5;
    for (int cc = lc; cc < 32; cc += 8) {
      int c = c0 + cc, p = p0 + lp;
      t[cc][lp] = (c < C && p < P) ? in[((size_t)b*C + c)*P + p] : 0.f;
    }
    __syncthreads();
    for (int pp = lc; pp < 32; pp += 8) {
      int p = p0 + pp, c = c0 + lp;
      if (p < P && c < C) out[((size_t)b*P + p)*C + c] = t[lp][pp];
    }
  } else if (bid < 8610) {
    int wave = threadIdx.x >> 6, lane = threadIdx.x & 63;
    int row = (bid - 6144) * 4 + wave;
    const float* Ar = adj + (size_t)row * N_;
    int* cp = cols + (size_t)row * ELLW;
    unsigned long long below = (lane == 63) ? 0xFFFFFFFFFFFFFFFFull >> 1
                                            : ((1ull << lane) - 1ull);
    int base = 0;
    for (int i0 = 0; i0 < 20; i0++) {
      int j0 = i0 * 128 + lane * 2;
      float2 v = make_float2(0.f, 0.f);
      if (j0 + 1 < N_) v = *(const float2*)&Ar[j0];
      bool nz0 = (j0 < N_) && (v.x != 0.f);
      bool nz1 = (j0 + 1 < N_) && (v.y != 0.f);
      unsigned long long m0 = __ballot(nz0);
      unsigned long long m1 = __ballot(nz1);
      int pre = __popcll(m0 & below) + __popcll(m1 & below);
      int p0 = base + pre;
      int p1 = p0 + (nz0 ? 1 : 0);
      if (nz0 && p0 < ELLW) cp[p0] = j0;
      if (nz1 && p1 < ELLW) cp[p1] = j0 + 1;
      base += __popcll(m0) + __popcll(m1);
    }
    if (lane == 0) cnts[row] = (base > ELLW) ? ELLW : base;
  } else if (bid < 9090) {
    // lin_w -> bf16 hi/lo fragments (491520 elems)
    int b = bid - 8610;
    int e0 = (b * 256 + threadIdx.x) * 4;
    #pragma unroll
    for (int u = 0; u < 4; u++) {
      int e = e0 + u;
      int j = e & 7;
      int lane = (e >> 3) & 63;
      int nt = (e >> 9) & 7;
      int slab = e >> 12;
      int k = slab * 32 + ((lane >> 4) << 3) + j;
      int n = nt * 16 + (lane & 15);
      float x = lin_w[(size_t)k * 128 + n];
      unsigned short h = bf16_rne(x);
      whi[e] = h;
      wlo[e] = bf16_rne(x - bf16_back(h));
    }
  } else {
    // res weights -> bf16 hi/lo fragments (307200 elems, zero-padded past K)
    int b = bid - 9090;                 // 0..299
    int e0 = (b * 256 + threadIdx.x) * 4;
    #pragma unroll
    for (int u = 0; u < 4; u++) {
      int e = e0 + u;
      int rb, mat, rem, K;
      if (e < 143360) {
        rb = 0;
        if (e < 110592) { mat = e / 36864; rem = e - mat * 36864; K = 259; }
        else { int tt = e - 110592; mat = 3 + tt / 16384; rem = tt & 16383; K = 128; }
      } else {
        int tt = e - 143360;
        rb = 1 + tt / 81920;
        int r2 = tt % 81920;
        mat = r2 / 16384; rem = r2 & 16383; K = 128;
      }
      int j = rem & 7, lane = (rem >> 3) & 63, nt = (rem >> 9) & 7, slab = rem >> 12;
      int k = slab * 32 + ((lane >> 4) << 3) + j;
      int n = nt * 16 + (lane & 15);
      float x = (k < K) ? wm.p[rb * 5 + mat][(size_t)k * 128 + n] : 0.f;
      unsigned short h = bf16_rne(x);
      wrh[e] = h;
      wrl[e] = bf16_rne(x - bf16_back(h));
    }
  }
}

// ============ split-K vertex-align gather + bf16x3 MFMA GEMM (R10-proven body) ============
// 512-thread blocks: 8 waves, each wave owns one 16-row m-tile -> M=128/block.
// NOTE: A-prefetch pipelining regressed this kernel (R11: 88->112 us); keep plain.
__global__ __launch_bounds__(512) void k_align_mfma(
    const float* __restrict__ tr0, const float* __restrict__ tr1,
    const float* __restrict__ tr2, const float* __restrict__ tr3,
    const float* __restrict__ pos,
    const unsigned short* __restrict__ whi, const unsigned short* __restrict__ wlo,
    float* __restrict__ part, int kchunk) {
  int tid  = threadIdx.x;
  int wave = tid >> 6, lane = tid & 63;
  int q    = lane >> 4, l15 = lane & 15;
  int m0   = blockIdx.x * 128;
  int s    = blockIdx.y;
  int mrow = m0 + wave * 16 + l15;

  float wgt[4]; int base[4];
  {
    int rowc = (mrow < R_) ? mrow : 0;
    int b = rowc / N_;
    float px = pos[rowc*3+0], py = pos[rowc*3+1], pz = pos[rowc*3+2];
    float hh = fminf(fmaxf(248.f*(py/pz)    + 111.5f, 0.f), 223.f);
    float wc = fminf(fmaxf(248.f*(px/(-pz)) + 111.5f, 0.f), 223.f);
    const int Sarr[4] = {56, 28, 14, 7};
    const int Carr[4] = {256, 512, 1024, 2048};
    #pragma unroll
    for (int sc = 0; sc < 4; sc++) {
      int S = Sarr[sc], C = Carr[sc];
      float dv = 224.f / (float)S;
      float x = hh / dv, y = wc / dv;
      int x1 = (int)floorf(x), y1 = (int)floorf(y);
      int x2 = min((int)ceilf(x), S - 1), y2 = min((int)ceilf(y), S - 1);
      float w = (float)((x2 - x1) * (y2 - y1));   // xi==x1,yi==y1 -> single tap
      if (mrow >= R_) w = 0.f;
      wgt[sc]  = w;
      base[sc] = (b * S * S + x1 * S + y1) * C;   // NHWC; add channel
    }
  }

  f32x4 acc[8];
  #pragma unroll
  for (int nt = 0; nt < 8; nt++) acc[nt] = (f32x4){0.f, 0.f, 0.f, 0.f};

  const bf16x8* BH = (const bf16x8*)whi;
  const bf16x8* BL = (const bf16x8*)wlo;

  int kbeg = s * kchunk, kend = kbeg + kchunk;
  #pragma unroll 1
  for (int k0 = kbeg; k0 < kend; k0 += 32) {
    const float* tr; int off, sI;
    if (k0 < 256)       { tr = tr0; off = 0;    sI = 0; }
    else if (k0 < 768)  { tr = tr1; off = 256;  sI = 1; }
    else if (k0 < 1792) { tr = tr2; off = 768;  sI = 2; }
    else                { tr = tr3; off = 1792; sI = 3; }

    const float* src = tr + base[sI] + (k0 - off + q * 8);
    float4 a0 = *(const float4*)src;
    float4 a1 = *(const float4*)(src + 4);
    float wg = wgt[sI];
    float af[8] = {a0.x*wg, a0.y*wg, a0.z*wg, a0.w*wg,
                   a1.x*wg, a1.y*wg, a1.z*wg, a1.w*wg};
    bf16x8 ahi, alo;
    #pragma unroll
    for (int j = 0; j < 8; j++) {
      unsigned short h = bf16_rne(af[j]);
      ahi[j] = (short)h;
      alo[j] = (short)bf16_rne(af[j] - bf16_back(h));
    }

    int slab = k0 >> 5;
    bf16x8 Bh[8], Bl[8];
    #pragma unroll
    for (int nt = 0; nt < 8; nt++) {
      size_t fi = (size_t)(slab * 8 + nt) * 64 + lane;
      Bh[nt] = BH[fi];
      Bl[nt] = BL[fi];
    }
    // hi*hi + lo*hi + hi*lo (lo*lo dropped)
    #pragma unroll
    for (int nt = 0; nt < 8; nt++)
      acc[nt] = __builtin_amdgcn_mfma_f32_16x16x32_bf16(ahi, Bh[nt], acc[nt], 0, 0, 0);
    #pragma unroll
    for (int nt = 0; nt < 8; nt++)
      acc[nt] = __builtin_amdgcn_mfma_f32_16x16x32_bf16(alo, Bh[nt], acc[nt], 0, 0, 0);
    #pragma unroll
    for (int nt = 0; nt < 8; nt++)
      acc[nt] = __builtin_amdgcn_mfma_f32_16x16x32_bf16(ahi, Bl[nt], acc[nt], 0, 0, 0);
  }

  // C/D layout: col = lane&15, row_in_tile = q*4 + reg
  #pragma unroll
  for (int nt = 0; nt < 8; nt++)
    #pragma unroll
    for (int r = 0; r < 4; r++) {
      int row = m0 + wave * 16 + q * 4 + r;
      if (row < R_)
        part[((size_t)s * R_ + row) * 128 + nt * 16 + l15] = acc[nt][r];
    }
}

// ---------------- reduce partials + bias, build xcat (proj|vf|pos|0pad), stride 288 ----------------
__global__ __launch_bounds__(256) void k_reduce(
    const float* __restrict__ part, const float* __restrict__ lin_b,
    const float* __restrict__ vf, const float* __restrict__ pos,
    float* __restrict__ xcat, int nsplit) {
  int row = blockIdx.x * 2 + (threadIdx.x >> 7);
  int k = threadIdx.x & 127;
  float acc = lin_b[k];
  for (int s = 0; s < nsplit; s++)
    acc += part[((size_t)s*R_ + row)*128 + k];
  xcat[(size_t)row*288 + k]       = acc;
  xcat[(size_t)row*288 + 128 + k] = vf[(size_t)row*128 + k];
  if (k < 32) xcat[(size_t)row*288 + 256 + k] = (k < 3) ? pos[(size_t)row*3 + k] : 0.f;
}

// ============ bf16x3 MFMA GEMM: out[which] = X @ W[which] (+pb for which==2) ============
// M=64/block (4 waves x 16-row m-tiles), N=128, W pre-split in fragment order.
template<int SLABS>
__global__ __launch_bounds__(256) void k_gemm_mfma(
    const float* __restrict__ X, int ldx,
    const unsigned short* __restrict__ wh, const unsigned short* __restrict__ wl,
    int matStride, const float* __restrict__ pb,
    float* __restrict__ o0, float* __restrict__ o1, float* __restrict__ o2) {
  int tid = threadIdx.x;
  int wave = tid >> 6, lane = tid & 63;
  int q = lane >> 4, l15 = lane & 15;
  int which = blockIdx.y;
  int m0 = blockIdx.x * 64;
  int mrow = m0 + wave * 16 + l15;
  int rowc = (mrow < R_) ? mrow : (R_ - 1);
  const float* xrow = X + (size_t)rowc * ldx + q * 8;

  const bf16x8* BH = (const bf16x8*)(wh + (size_t)which * matStride);
  const bf16x8* BL = (const bf16x8*)(wl + (size_t)which * matStride);

  f32x4 acc[8];
  #pragma unroll
  for (int nt = 0; nt < 8; nt++) acc[nt] = (f32x4){0.f, 0.f, 0.f, 0.f};

  #pragma unroll 1
  for (int slab = 0; slab < SLABS; slab++) {
    const float* src = xrow + slab * 32;
    float4 a0 = *(const float4*)src;
    float4 a1 = *(const float4*)(src + 4);
    float af[8] = {a0.x, a0.y, a0.z, a0.w, a1.x, a1.y, a1.z, a1.w};
    bf16x8 ahi, alo;
    #pragma unroll
    for (int j = 0; j < 8; j++) {
      unsigned short h = bf16_rne(af[j]);
      ahi[j] = (short)h;
      alo[j] = (short)bf16_rne(af[j] - bf16_back(h));
    }
    bf16x8 Bh[8], Bl[8];
    #pragma unroll
    for (int nt = 0; nt < 8; nt++) {
      size_t fi = (size_t)(slab * 8 + nt) * 64 + lane;
      Bh[nt] = BH[fi];
      Bl[nt] = BL[fi];
    }
    #pragma unroll
    for (int nt = 0; nt < 8; nt++)
      acc[nt] = __builtin_amdgcn_mfma_f32_16x16x32_bf16(ahi, Bh[nt], acc[nt], 0, 0, 0);
    #pragma unroll
    for (int nt = 0; nt < 8; nt++)
      acc[nt] = __builtin_amdgcn_mfma_f32_16x16x32_bf16(alo, Bh[nt], acc[nt], 0, 0, 0);
    #pragma unroll
    for (int nt = 0; nt < 8; nt++)
      acc[nt] = __builtin_amdgcn_mfma_f32_16x16x32_bf16(ahi, Bl[nt], acc[nt], 0, 0, 0);
  }

  float* out = (which == 0) ? o0 : (which == 1) ? o1 : o2;
  #pragma unroll
  for (int nt = 0; nt < 8; nt++) {
    int col = nt * 16 + l15;
    float bias = (pb != nullptr && which == 2) ? pb[col] : 0.f;
    #pragma unroll
    for (int r = 0; r < 4; r++) {
      int row = m0 + wave * 16 + q * 4 + r;
      if (row < R_) out[(size_t)row * 128 + col] = acc[nt][r] + bias;
    }
  }
}

// ---------------- SpMM: out = [skip +] relu(s + A@t); optional fused 128->3 GEMV ----------------
__global__ __launch_bounds__(256) void k_spmm(
    const float* __restrict__ sb, const float* __restrict__ tb,
    const int* __restrict__ cols, const int* __restrict__ cnts,
    const float* __restrict__ skipb, float* __restrict__ outb,
    const float* __restrict__ gw0, const float* __restrict__ gw1,
    float* __restrict__ gsb, float* __restrict__ gtb, int fuse_gf) {
  int tid = threadIdx.x;
  int grp = tid >> 5, ln = tid & 31;
  int row = blockIdx.x * 8 + grp;           // 1233 * 8 = 9864 exact
  int b = row / N_;
  size_t tbase = (size_t)b * N_;
  const float4* sb4 = (const float4*)sb;
  const float4* tb4 = (const float4*)tb;
  float4 acc = sb4[(size_t)row*32 + ln];
  int cnt = cnts[row];
  const int* cp = cols + (size_t)row * ELLW;
  for (int i = 0; i < cnt; i++) {
    int c = cp[i];
    float4 v = tb4[(tbase + c)*32 + ln];
    acc.x += v.x; acc.y += v.y; acc.z += v.z; acc.w += v.w;
  }
  acc.x = fmaxf(acc.x, 0.f); acc.y = fmaxf(acc.y, 0.f);
  acc.z = fmaxf(acc.z, 0.f); acc.w = fmaxf(acc.w, 0.f);
  if (skipb) {
    float4 sv = ((const float4*)skipb)[(size_t)row*32 + ln];
    acc.x += sv.x; acc.y += sv.y; acc.z += sv.z; acc.w += sv.w;
  }
  if (!fuse_gf) {
    ((float4*)outb)[(size_t)row*32 + ln] = acc;
    return;
  }
  float av[4] = {acc.x, acc.y, acc.z, acc.w};
  int j0 = ln * 4;
  float p0 = 0.f, p1 = 0.f, p2 = 0.f, q0 = 0.f, q1 = 0.f, q2 = 0.f;
  #pragma unroll
  for (int u = 0; u < 4; u++) {
    int j = j0 + u;
    p0 += av[u] * gw0[j*3+0]; p1 += av[u] * gw0[j*3+1]; p2 += av[u] * gw0[j*3+2];
    q0 += av[u] * gw1[j*3+0]; q1 += av[u] * gw1[j*3+1]; q2 += av[u] * gw1[j*3+2];
  }
  #pragma unroll
  for (int off = 16; off >= 1; off >>= 1) {
    p0 += __shfl_xor(p0, off); p1 += __shfl_xor(p1, off); p2 += __shfl_xor(p2, off);
    q0 += __shfl_xor(q0, off); q1 += __shfl_xor(q1, off); q2 += __shfl_xor(q2, off);
  }
  if (ln == 0) {
    gsb[(size_t)row*128 + 0] = p0; gsb[(size_t)row*128 + 1] = p1; gsb[(size_t)row*128 + 2] = p2;
    gtb[(size_t)row*128 + 0] = q0; gtb[(size_t)row*128 + 1] = q1; gtb[(size_t)row*128 + 2] = q2;
  }
}

// ---------------- final: out = pos + tanh(relu(s + A@t)) ----------------
__global__ __launch_bounds__(256) void k_gf_final(
    const float* __restrict__ sb, const float* __restrict__ tb,
    const int* __restrict__ cols, const int* __restrict__ cnts,
    const float* __restrict__ pos, float* __restrict__ out) {
  int wave = threadIdx.x >> 6, lane = threadIdx.x & 63;
  int row = blockIdx.x * 4 + wave;          // grid 2466
  if (lane >= 3) return;
  int b = row / N_;
  float acc = sb[(size_t)row*128 + lane];
  int cnt = cnts[row];
  const int* cp = cols + (size_t)row * ELLW;
  size_t tbase = (size_t)b * N_;
  for (int i = 0; i < cnt; i++)
    acc += tb[(tbase + cp[i])*128 + lane];
  float v = tanhf(fmaxf(acc, 0.f));
  out[(size_t)row*3 + lane] = pos[(size_t)row*3 + lane] + v;
}

extern "C" void kernel_launch(void* const* d_in, const int* in_sizes, int n_in,
                              void* d_out, int out_size, void* d_ws, size_t ws_size,
                              hipStream_t stream) {
  const float* conv2_3 = (const float*)d_in[0];
  const float* conv3_4 = (const float*)d_in[1];
  const float* conv4_6 = (const float*)d_in[2];
  const float* conv5_3 = (const float*)d_in[3];
  const float* pos     = (const float*)d_in[4];
  const float* vf      = (const float*)d_in[5];
  const float* adj     = (const float*)d_in[6];
  const float* lin_w   = (const float*)d_in[7];
  const float* lin_b   = (const float*)d_in[8];
  const float* r_pb[3]  = {(const float*)d_in[10], (const float*)d_in[16], (const float*)d_in[22]};
  const float* gf_w0 = (const float*)d_in[27];
  const float* gf_w1 = (const float*)d_in[28];
  float* out = (float*)d_out;

  // ---- workspace layout (float slots) ----
  const size_t TR_TOT  = (size_t)4*(256*3136 + 512*784 + 1024*196 + 2048*49); // 6,021,120
  const size_t ROWF    = (size_t)R_ * 128;                                    // 1,262,592
  const size_t XCAT_F  = (size_t)R_ * 288;                                    // 2,840,832
  const size_t LINW_E  = 491520;                                              // shorts per array
  const size_t RESW_E  = 307200;                                              // shorts per array

  float* ws  = (float*)d_ws;
  float* tr0 = ws;
  float* tr1 = tr0 + (size_t)4*256*3136;
  float* tr2 = tr1 + (size_t)4*512*784;
  float* tr3 = tr2 + (size_t)4*1024*196;
  int*   ell_cnt  = (int*)(tr3 + (size_t)4*2048*49);
  int*   ell_cols = ell_cnt + R_;
  unsigned short* whi = (unsigned short*)(ell_cols + (size_t)R_*ELLW);
  unsigned short* wlo = whi + LINW_E;
  unsigned short* wrh = wlo + LINW_E;
  unsigned short* wrl = wrh + RESW_E;
  float* part = (float*)(wrl + RESW_E);

  size_t fixed_f = TR_TOT + (size_t)R_*(ELLW+1) + LINW_E + RESW_E;
  size_t need8 = (fixed_f + (size_t)8*ROWF + XCAT_F + 5*ROWF) * sizeof(float);
  int nsplit = (ws_size >= need8) ? 8 : 4;
  int kchunk = 3840 / nsplit;

  float* xcat = part + (size_t)nsplit * ROWF;
  float* sb   = xcat + XCAT_F;
  float* tb   = sb   + ROWF;
  float* skip = tb   + ROWF;
  float* hb   = skip + ROWF;
  float* xc   = hb   + ROWF;

  WMats wm;
  for (int rb = 0; rb < 3; rb++) {
    wm.p[rb*5 + 0] = (const float*)d_in[11 + 6*rb];  // w00
    wm.p[rb*5 + 1] = (const float*)d_in[12 + 6*rb];  // w01
    wm.p[rb*5 + 2] = (const float*)d_in[9  + 6*rb];  // pw
    wm.p[rb*5 + 3] = (const float*)d_in[13 + 6*rb];  // w10
    wm.p[rb*5 + 4] = (const float*)d_in[14 + 6*rb];  // w11
  }
  const int RB_BASE[3] = {0, 143360, 225280};

  // D0: transposes + ELL + all W splits
  k_pre<<<9390, 256, 0, stream>>>(conv2_3, conv3_4, conv4_6, conv5_3,
                                  tr0, tr1, tr2, tr3,
                                  adj, ell_cols, ell_cnt,
                                  lin_w, whi, wlo, wm, wrh, wrl);

  // D1: split-K MFMA align GEMM (512-thread blocks, M=128, no prefetch — R10 body)
  k_align_mfma<<<dim3(78, nsplit), 512, 0, stream>>>(tr0, tr1, tr2, tr3, pos,
                                                     whi, wlo, part, kchunk);

  // D2: reduce partials + concat (stride 288, zero-padded)
  k_reduce<<<4932, 256, 0, stream>>>(part, lin_b, vf, pos, xcat, nsplit);

  // D3..: three residual graph-conv blocks, all GEMMs via bf16x3 MFMA
  for (int rb = 0; rb < 3; rb++) {
    if (rb == 0) {
      k_gemm_mfma<9><<<dim3(155, 3), 256, 0, stream>>>(
          xcat, 288, wrh + RB_BASE[0], wrl + RB_BASE[0], 36864, r_pb[0], sb, tb, skip);
    } else {
      k_gemm_mfma<4><<<dim3(155, 3), 256, 0, stream>>>(
          xc, 128, wrh + RB_BASE[rb], wrl + RB_BASE[rb], 16384, r_pb[rb], sb, tb, skip);
    }
    k_spmm<<<1233, 256, 0, stream>>>(sb, tb, ell_cols, ell_cnt, nullptr, hb,
                                     nullptr, nullptr, nullptr, nullptr, 0);
    int g2off = RB_BASE[rb] + ((rb == 0) ? 110592 : 3 * 16384);
    k_gemm_mfma<4><<<dim3(155, 2), 256, 0, stream>>>(
        hb, 128, wrh + g2off, wrl + g2off, 16384, nullptr, sb, tb, nullptr);
    if (rb < 2) {
      k_spmm<<<1233, 256, 0, stream>>>(sb, tb, ell_cols, ell_cnt, skip, xc,
                                       nullptr, nullptr, nullptr, nullptr, 0);
    } else {
      k_spmm<<<1233, 256, 0, stream>>>(sb, tb, ell_cols, ell_cnt, skip, nullptr,
                                       gf_w0, gf_w1, hb, xc, 1);   // gsb=hb, gtb=xc
    }
  }

  // final: out = pos + tanh(relu(gsb + A@gtb))
  k_gf_final<<<2466, 256, 0, stream>>>(hb, xc, ell_cols, ell_cnt, pos, out);
}